// Round 10
// baseline (2612.275 us; speedup 1.0000x reference)
//
#include <hip/hip_runtime.h>
#include <cstddef>
#include <cstdint>

#define NTOTC 16384
#define HC 256
#define LC 6
#define NEDGEC 262144
#define NHEADSC 8

typedef __attribute__((ext_vector_type(8))) short short8;
typedef __attribute__((ext_vector_type(4))) float f32x4;

__device__ __forceinline__ unsigned short f2bf(float f) {
    unsigned int u = __float_as_uint(f);
    u += 0x7fff + ((u >> 16) & 1);   // round-to-nearest-even
    return (unsigned short)(u >> 16);
}
__device__ __forceinline__ float bf2f(unsigned short s) {
    return __uint_as_float(((unsigned int)s) << 16);
}
__device__ __forceinline__ void async_copy16(const void* g, void* l) {
    __builtin_amdgcn_global_load_lds(
        (const __attribute__((address_space(1))) unsigned int*)g,
        (__attribute__((address_space(3))) unsigned int*)l, 16, 0, 0);
}
// fast transcendentals; ~1e-6 rel err, negligible vs bf16
__device__ __forceinline__ float exp_f(float v) {
    return __builtin_amdgcn_exp2f(v * 1.4426950408889634f);
}
__device__ __forceinline__ float silu_f(float v) {
    return v * __builtin_amdgcn_rcpf(1.0f + __builtin_amdgcn_exp2f(-v * 1.4426950408889634f));
}
__device__ __forceinline__ float tanh_f(float v) {
    float e = __builtin_amdgcn_exp2f(v * 2.8853900817779268f);   // e^(2v)
    return 1.0f - 2.0f * __builtin_amdgcn_rcpf(1.0f + e);
}

// ================= weight conversion =================
__global__ __launch_bounds__(256) void conv_bf16_kernel(
    const float* __restrict__ in, unsigned short* __restrict__ out, int n)
{
    for (int i = blockIdx.x * 256 + threadIdx.x; i < n; i += gridDim.x * 256)
        out[i] = f2bf(in[i]);
}

// phi_e_w1 [L,256,513] -> stacked bf16 [L,512,256] ([W1a;W1b]) + fp32 dist column [L,256]
__global__ __launch_bounds__(256) void conv_pe1_kernel(
    const float* __restrict__ in, unsigned short* __restrict__ outk, float* __restrict__ wlast)
{
    int idx = blockIdx.x * 256 + threadIdx.x;
    if (idx >= LC * 256 * 513) return;
    int l = idx / (256 * 513);
    int rem = idx % (256 * 513);
    int n = rem / 513;
    int k = rem % 513;
    float v = in[idx];
    if (k == 512) wlast[l * 256 + n] = v;
    else if (k < 256) outk[(size_t)l * 512 * 256 + (size_t)n * 256 + k] = f2bf(v);
    else outk[(size_t)l * 512 * 256 + (size_t)(256 + n) * 256 + (k - 256)] = f2bf(v);
}

// ================= counting sort of edges by col =================
__global__ __launch_bounds__(256) void hist_kernel(
    const int* __restrict__ col, int* __restrict__ cnt)
{
    int e = blockIdx.x * 256 + threadIdx.x;
    atomicAdd(&cnt[col[e]], 1);
}

__global__ __launch_bounds__(256) void scan16k_kernel(
    const int* __restrict__ cnt, int* __restrict__ ptrw)
{
    __shared__ int partial[256];
    const int t = threadIdx.x;
    const int base = t * 64;
    int loc[64];
    int s = 0;
#pragma unroll
    for (int i = 0; i < 64; i++) { loc[i] = s; s += cnt[base + i]; }
    partial[t] = s;
    __syncthreads();
    if (t == 0) {
        int run = 0;
        for (int i = 0; i < 256; i++) { int tmp = partial[i]; partial[i] = run; run += tmp; }
    }
    __syncthreads();
    int off = partial[t];
#pragma unroll
    for (int i = 0; i < 64; i++) ptrw[base + i] = off + loc[i];
}

__global__ __launch_bounds__(256) void permute_kernel(
    const int* __restrict__ row, const int* __restrict__ col, int* __restrict__ ptrw,
    int* __restrict__ rowP, int* __restrict__ colP)
{
    int e = blockIdx.x * 256 + threadIdx.x;
    int c = col[e];
    int pos = atomicAdd(&ptrw[c], 1);
    rowP[pos] = row[e];
    colP[pos] = c;
}

// ================= generic MFMA GEMM: C = act(A @ W^T + bias)(+R) =================
template<int ACT, bool RES, bool WF, bool WB>
__global__ __launch_bounds__(256) void mgemm_kernel(
    const unsigned short* __restrict__ A, const unsigned short* __restrict__ W,
    const float* __restrict__ bias, const float* __restrict__ R,
    float* __restrict__ Cf, unsigned short* __restrict__ Cb,
    int M, int N, int K)
{
    __shared__ unsigned short As[128 * 32];
    __shared__ unsigned short Bs[128 * 32];
    const int tid = threadIdx.x;
    const int lane = tid & 63, wave = tid >> 6;
    const int quad = lane >> 4, l16 = lane & 15;
    const int wm = (wave >> 1) * 64, wn = (wave & 1) * 64;
    const int m0 = blockIdx.x * 128, n0 = blockIdx.y * 128;
    f32x4 acc[4][4] = {};
    const int rbase = (lane >> 2);
    const int kk = (lane & 3) * 8;

    for (int k0 = 0; k0 < K; k0 += 32) {
#pragma unroll
        for (int c = 0; c < 2; c++) {
            int t = wave * 2 + c;
            int r = t * 16 + rbase;
            async_copy16(A + (size_t)(m0 + r) * K + k0 + kk, &As[t * 512 + lane * 8]);
            async_copy16(W + (size_t)(n0 + r) * K + k0 + kk, &Bs[t * 512 + lane * 8]);
        }
        __syncthreads();
        short8 af[4], bfr[4];
#pragma unroll
        for (int i = 0; i < 4; i++)
            af[i] = *(const short8*)&As[(wm + i * 16 + l16) * 32 + quad * 8];
#pragma unroll
        for (int j = 0; j < 4; j++)
            bfr[j] = *(const short8*)&Bs[(wn + j * 16 + l16) * 32 + quad * 8];
#pragma unroll
        for (int i = 0; i < 4; i++)
#pragma unroll
            for (int j = 0; j < 4; j++)
                acc[i][j] = __builtin_amdgcn_mfma_f32_16x16x32_bf16(af[i], bfr[j], acc[i][j], 0, 0, 0);
        __syncthreads();
    }
#pragma unroll
    for (int j = 0; j < 4; j++) {
        int col = n0 + wn + j * 16 + l16;
        float bi = bias[col];
#pragma unroll
        for (int i = 0; i < 4; i++) {
#pragma unroll
            for (int rg = 0; rg < 4; rg++) {
                int row = m0 + wm + i * 16 + quad * 4 + rg;
                float v = acc[i][j][rg] + bi;
                if (ACT == 1) v = silu_f(v);
                if (ACT == 2) v = 0.5f * v * (1.0f + erff(v * 0.7071067811865476f));
                if (RES) v += R[(size_t)row * N + col];
                if (WF) Cf[(size_t)row * N + col] = v;
                if (WB) Cb[(size_t)row * N + col] = f2bf(v);
            }
        }
    }
}

// ================= FUSED edge pipeline: 128 edges/block =================
__global__ __launch_bounds__(256, 2) void fused_edge_kernel(
    const unsigned short* __restrict__ xcat,
    const int* __restrict__ rowP, const int* __restrict__ colP,
    const float* __restrict__ distv, const float* __restrict__ relv,
    const float* __restrict__ wlast, const float* __restrict__ b1,
    const unsigned short* __restrict__ W2, const float* __restrict__ b2,
    const float* __restrict__ lg, const float* __restrict__ lb,
    const unsigned short* __restrict__ W3, const float* __restrict__ b3,
    const float* __restrict__ w2v, const float* __restrict__ b2s,
    float* __restrict__ hmsg, float* __restrict__ posupd)
{
    __shared__ __align__(16) unsigned short tS[128 * 264];   // 67.6 KB
    __shared__ float redS[4][128];
    __shared__ float redS2[4][128];
    __shared__ int rowS[128], colS[128], flagS[128];
    __shared__ float distS[128];
    __shared__ float relS[128][3];
    __shared__ float cfS[128];

    const int tid = threadIdx.x;
    const int lane = tid & 63, wave = tid >> 6;
    const int quad = lane >> 4, l16 = lane & 15;
    const int wn = wave * 64;
    const int m0 = blockIdx.x * 128;

    if (tid < 128) {
        rowS[tid] = rowP[m0 + tid];
        colS[tid] = colP[m0 + tid];
        distS[tid] = distv[m0 + tid];
        relS[tid][0] = relv[(size_t)(m0 + tid) * 3 + 0];
        relS[tid][1] = relv[(size_t)(m0 + tid) * 3 + 1];
        relS[tid][2] = relv[(size_t)(m0 + tid) * 3 + 2];
    }
    __syncthreads();
    if (tid < 128) flagS[tid] = (tid == 127) || (colS[tid] != colS[tid + 1]);

    // ---- Stage 1: gather-add replacing edge GEMM1 ----
    {
        const int cb = lane * 4;
        float4 wl4 = *(const float4*)&wlast[cb];
        float4 b14 = *(const float4*)&b1[cb];
#pragma unroll
        for (int rr = 0; rr < 32; rr++) {
            int r = rr * 4 + wave;
            const ushort4 ua = *(const ushort4*)(xcat + (size_t)rowS[r] * 512 + cb);
            const ushort4 ub = *(const ushort4*)(xcat + (size_t)colS[r] * 512 + 256 + cb);
            float dv = distS[r];
            float v0 = bf2f(ua.x) + bf2f(ub.x) + dv * wl4.x + b14.x;
            float v1 = bf2f(ua.y) + bf2f(ub.y) + dv * wl4.y + b14.y;
            float v2 = bf2f(ua.z) + bf2f(ub.z) + dv * wl4.z + b14.z;
            float v3 = bf2f(ua.w) + bf2f(ub.w) + dv * wl4.w + b14.w;
            ushort4 o;
            o.x = f2bf(silu_f(v0));
            o.y = f2bf(silu_f(v1));
            o.z = f2bf(silu_f(v2));
            o.w = f2bf(silu_f(v3));
            *(ushort4*)&tS[r * 264 + cb] = o;
        }
    }
    __syncthreads();

    f32x4 acc[8][4];

    // ---- GEMM2: M=128, K=256, A from tS, W2 direct; NO barriers ----
#pragma unroll
    for (int i = 0; i < 8; i++)
#pragma unroll
        for (int j = 0; j < 4; j++) acc[i][j] = (f32x4){0.f, 0.f, 0.f, 0.f};
#pragma unroll
    for (int k0 = 0; k0 < 256; k0 += 32) {
        short8 af[8], bfr[4];
#pragma unroll
        for (int j = 0; j < 4; j++)
            bfr[j] = *(const short8*)(W2 + (size_t)(wn + j * 16 + l16) * 256 + k0 + quad * 8);
#pragma unroll
        for (int i = 0; i < 8; i++)
            af[i] = *(const short8*)&tS[(i * 16 + l16) * 264 + k0 + quad * 8];
#pragma unroll
        for (int i = 0; i < 8; i++)
#pragma unroll
            for (int j = 0; j < 4; j++)
                acc[i][j] = __builtin_amdgcn_mfma_f32_16x16x32_bf16(af[i], bfr[j], acc[i][j], 0, 0, 0);
    }
    __syncthreads();
    // epilogue 2: LN -> m -> tS (overwrite)
    {
        float b2j[4], gj[4], bbj[4];
#pragma unroll
        for (int j = 0; j < 4; j++) {
            int col = wn + j * 16 + l16;
            b2j[j] = b2[col];
            gj[j] = lg[col];
            bbj[j] = lb[col];
        }
#pragma unroll
        for (int i = 0; i < 8; i++)
#pragma unroll
            for (int rg = 0; rg < 4; rg++) {
                float p = 0.0f, q = 0.0f;
#pragma unroll
                for (int j = 0; j < 4; j++) {
                    float v = acc[i][j][rg] + b2j[j];
                    p += v; q += v * v;
                }
#pragma unroll
                for (int off = 1; off < 16; off <<= 1) {
                    p += __shfl_xor(p, off);
                    q += __shfl_xor(q, off);
                }
                if (l16 == 0) {
                    int row = i * 16 + quad * 4 + rg;
                    redS[wave][row] = p;
                    redS2[wave][row] = q;
                }
            }
        __syncthreads();
#pragma unroll
        for (int i = 0; i < 8; i++)
#pragma unroll
            for (int rg = 0; rg < 4; rg++) {
                int row = i * 16 + quad * 4 + rg;
                float s = redS[0][row] + redS[1][row] + redS[2][row] + redS[3][row];
                float qq = redS2[0][row] + redS2[1][row] + redS2[2][row] + redS2[3][row];
                float mean = s * (1.0f / 256.0f);
                float rstd = 1.0f / sqrtf(qq * (1.0f / 256.0f) - mean * mean + 1e-5f);
#pragma unroll
                for (int j = 0; j < 4; j++) {
                    int col = wn + j * 16 + l16;
                    float v = acc[i][j][rg] + b2j[j];
                    tS[row * 264 + col] = f2bf((v - mean) * rstd * gj[j] + bbj[j]);
                }
            }
    }
    __syncthreads();

    // ---- segmented scatter of m into hmsg ----
    {
        const int c = tid;
        float s = 0.0f;
#pragma unroll
        for (int r = 0; r < 128; r++) {
            s += bf2f(tS[r * 264 + c]);
            if (flagS[r]) {
                atomicAdd(&hmsg[(size_t)colS[r] * 256 + c], s);
                s = 0.0f;
            }
        }
    }

    // ---- GEMM3: M=128, K=256, A = m from tS, W3 direct ----
#pragma unroll
    for (int i = 0; i < 8; i++)
#pragma unroll
        for (int j = 0; j < 4; j++) acc[i][j] = (f32x4){0.f, 0.f, 0.f, 0.f};
#pragma unroll
    for (int k0 = 0; k0 < 256; k0 += 32) {
        short8 af[8], bfr[4];
#pragma unroll
        for (int j = 0; j < 4; j++)
            bfr[j] = *(const short8*)(W3 + (size_t)(wn + j * 16 + l16) * 256 + k0 + quad * 8);
#pragma unroll
        for (int i = 0; i < 8; i++)
            af[i] = *(const short8*)&tS[(i * 16 + l16) * 264 + k0 + quad * 8];
#pragma unroll
        for (int i = 0; i < 8; i++)
#pragma unroll
            for (int j = 0; j < 4; j++)
                acc[i][j] = __builtin_amdgcn_mfma_f32_16x16x32_bf16(af[i], bfr[j], acc[i][j], 0, 0, 0);
    }
    // epilogue 3
    {
        float b3j[4], w2j[4];
#pragma unroll
        for (int j = 0; j < 4; j++) {
            int col = wn + j * 16 + l16;
            b3j[j] = b3[col];
            w2j[j] = w2v[col];
        }
#pragma unroll
        for (int i = 0; i < 8; i++)
#pragma unroll
            for (int rg = 0; rg < 4; rg++) {
                float p = 0.0f;
#pragma unroll
                for (int j = 0; j < 4; j++)
                    p += silu_f(acc[i][j][rg] + b3j[j]) * w2j[j];
#pragma unroll
                for (int off = 1; off < 16; off <<= 1) p += __shfl_xor(p, off);
                if (l16 == 0) redS[wave][i * 16 + quad * 4 + rg] = p;
            }
        __syncthreads();
        if (tid < 128) {
            float tot = redS[0][tid] + redS[1][tid] + redS[2][tid] + redS[3][tid] + b2s[0];
            cfS[tid] = tanh_f(tot);
        }
        __syncthreads();
        if (tid < 3) {
            const int comp = tid;
            float s = 0.0f;
#pragma unroll
            for (int r = 0; r < 128; r++) {
                s += relS[r][comp] * cfS[r];
                if (flagS[r]) {
                    atomicAdd(&posupd[(size_t)colS[r] * 3 + comp], s);
                    s = 0.0f;
                }
            }
        }
    }
}

// ============ phi_h fused: h = LN2(h + LN1(silu((h+hmsg)@W1^T+b1)@W2^T+b2)) ============
__global__ __launch_bounds__(256) void phi_h_fused_kernel(
    const float* __restrict__ h_in, const float* __restrict__ hmsg,
    const unsigned short* __restrict__ W1, const float* __restrict__ b1v,
    const unsigned short* __restrict__ W2, const float* __restrict__ bias,
    const float* __restrict__ g1, const float* __restrict__ bb1,
    const float* __restrict__ g2, const float* __restrict__ bb2,
    float* __restrict__ h, unsigned short* __restrict__ h_bf)
{
    __shared__ __align__(16) unsigned short As[64 * 32];
    __shared__ __align__(16) unsigned short Bs[256 * 32];
    __shared__ __align__(16) unsigned short tS[64 * 264];
    __shared__ float redS[4][64];
    __shared__ float redS2[4][64];
    const int tid = threadIdx.x;
    const int lane = tid & 63, wave = tid >> 6;
    const int quad = lane >> 4, l16 = lane & 15;
    const int wn = wave * 64;
    const int m0 = blockIdx.x * 64;
    f32x4 acc[4][4] = {};
    const int rbase = (lane >> 2);
    const int kk = (lane & 3) * 8;

    // ---- GEMM1: A = bf16(h+hmsg) staged via VGPR, B = W1 async ----
    for (int k0 = 0; k0 < 256; k0 += 32) {
#pragma unroll
        for (int c = 0; c < 2; c++) {
            int u = c * 256 + tid;
            int r = u >> 3, kg = (u & 7) * 4;
            float4 a = *(const float4*)&h_in[(size_t)(m0 + r) * 256 + k0 + kg];
            float4 b = *(const float4*)&hmsg[(size_t)(m0 + r) * 256 + k0 + kg];
            ushort4 o4;
            o4.x = f2bf(a.x + b.x);
            o4.y = f2bf(a.y + b.y);
            o4.z = f2bf(a.z + b.z);
            o4.w = f2bf(a.w + b.w);
            *(ushort4*)&As[r * 32 + kg] = o4;
        }
#pragma unroll
        for (int c = 0; c < 4; c++) {
            int t = wave * 4 + c;
            int r = t * 16 + rbase;
            async_copy16(W1 + (size_t)r * 256 + k0 + kk, &Bs[t * 512 + lane * 8]);
        }
        __syncthreads();
        short8 bfr[4];
#pragma unroll
        for (int j = 0; j < 4; j++)
            bfr[j] = *(const short8*)&Bs[(wn + j * 16 + l16) * 32 + quad * 8];
#pragma unroll
        for (int i = 0; i < 4; i++) {
            short8 af = *(const short8*)&As[(i * 16 + l16) * 32 + quad * 8];
#pragma unroll
            for (int j = 0; j < 4; j++)
                acc[i][j] = __builtin_amdgcn_mfma_f32_16x16x32_bf16(af, bfr[j], acc[i][j], 0, 0, 0);
        }
        __syncthreads();
    }
    // epilogue 1: t = silu(acc + b1) -> tS
    {
        float b1j[4];
#pragma unroll
        for (int j = 0; j < 4; j++) b1j[j] = b1v[wn + j * 16 + l16];
#pragma unroll
        for (int i = 0; i < 4; i++)
#pragma unroll
            for (int rg = 0; rg < 4; rg++) {
                int row = i * 16 + quad * 4 + rg;
#pragma unroll
                for (int j = 0; j < 4; j++) {
                    int col = wn + j * 16 + l16;
                    tS[row * 264 + col] = f2bf(silu_f(acc[i][j][rg] + b1j[j]));
                }
            }
    }
    __syncthreads();

    // ---- GEMM2: A from tS, W2 direct global; NO barriers ----
#pragma unroll
    for (int i = 0; i < 4; i++)
#pragma unroll
        for (int j = 0; j < 4; j++) acc[i][j] = (f32x4){0.f, 0.f, 0.f, 0.f};
#pragma unroll
    for (int k0 = 0; k0 < 256; k0 += 32) {
        short8 af[4], bfr[4];
#pragma unroll
        for (int j = 0; j < 4; j++)
            bfr[j] = *(const short8*)(W2 + (size_t)(wn + j * 16 + l16) * 256 + k0 + quad * 8);
#pragma unroll
        for (int i = 0; i < 4; i++)
            af[i] = *(const short8*)&tS[(i * 16 + l16) * 264 + k0 + quad * 8];
#pragma unroll
        for (int i = 0; i < 4; i++)
#pragma unroll
            for (int j = 0; j < 4; j++)
                acc[i][j] = __builtin_amdgcn_mfma_f32_16x16x32_bf16(af[i], bfr[j], acc[i][j], 0, 0, 0);
    }

    // ---- epilogue: hu = LN1(acc + bias); z = h + hu; h = LN2(z) ----
    float bj[4], g1j[4], b1j[4], g2j[4], b2j[4];
#pragma unroll
    for (int j = 0; j < 4; j++) {
        int col = wn + j * 16 + l16;
        bj[j] = bias[col];
        g1j[j] = g1[col]; b1j[j] = bb1[col];
        g2j[j] = g2[col]; b2j[j] = bb2[col];
    }
#pragma unroll
    for (int i = 0; i < 4; i++)
#pragma unroll
        for (int rg = 0; rg < 4; rg++) {
            float p = 0.0f, q = 0.0f;
#pragma unroll
            for (int j = 0; j < 4; j++) {
                float v = acc[i][j][rg] + bj[j];
                p += v; q += v * v;
            }
#pragma unroll
            for (int off = 1; off < 16; off <<= 1) {
                p += __shfl_xor(p, off);
                q += __shfl_xor(q, off);
            }
            if (l16 == 0) {
                int rl = i * 16 + quad * 4 + rg;
                redS[wave][rl] = p;
                redS2[wave][rl] = q;
            }
        }
    __syncthreads();
#pragma unroll
    for (int i = 0; i < 4; i++)
#pragma unroll
        for (int rg = 0; rg < 4; rg++) {
            int rl = i * 16 + quad * 4 + rg;
            float s = redS[0][rl] + redS[1][rl] + redS[2][rl] + redS[3][rl];
            float qq = redS2[0][rl] + redS2[1][rl] + redS2[2][rl] + redS2[3][rl];
            float mean = s * (1.0f / 256.0f);
            float rstd = 1.0f / sqrtf(qq * (1.0f / 256.0f) - mean * mean + 1e-5f);
#pragma unroll
            for (int j = 0; j < 4; j++) {
                int col = wn + j * 16 + l16;
                float v = acc[i][j][rg] + bj[j];
                float hu = (v - mean) * rstd * g1j[j] + b1j[j];
                acc[i][j][rg] = hu + h_in[(size_t)(m0 + rl) * 256 + col];
            }
        }
    __syncthreads();
#pragma unroll
    for (int i = 0; i < 4; i++)
#pragma unroll
        for (int rg = 0; rg < 4; rg++) {
            float p = 0.0f, q = 0.0f;
#pragma unroll
            for (int j = 0; j < 4; j++) {
                float v = acc[i][j][rg];
                p += v; q += v * v;
            }
#pragma unroll
            for (int off = 1; off < 16; off <<= 1) {
                p += __shfl_xor(p, off);
                q += __shfl_xor(q, off);
            }
            if (l16 == 0) {
                int rl = i * 16 + quad * 4 + rg;
                redS[wave][rl] = p;
                redS2[wave][rl] = q;
            }
        }
    __syncthreads();
#pragma unroll
    for (int i = 0; i < 4; i++)
#pragma unroll
        for (int rg = 0; rg < 4; rg++) {
            int rl = i * 16 + quad * 4 + rg;
            float s = redS[0][rl] + redS[1][rl] + redS[2][rl] + redS[3][rl];
            float qq = redS2[0][rl] + redS2[1][rl] + redS2[2][rl] + redS2[3][rl];
            float mean = s * (1.0f / 256.0f);
            float rstd = 1.0f / sqrtf(qq * (1.0f / 256.0f) - mean * mean + 1e-5f);
            size_t orow = (size_t)(m0 + rl) * 256;
#pragma unroll
            for (int j = 0; j < 4; j++) {
                int col = wn + j * 16 + l16;
                float y = (acc[i][j][rg] - mean) * rstd * g2j[j] + b2j[j];
                h[orow + col] = y;
                h_bf[orow + col] = f2bf(y);
            }
        }
}

// ============ fused node GEMM + LN epilogue (attn-out path) ============
template<bool LN2>
__global__ __launch_bounds__(256) void node_fused_kernel(
    const unsigned short* __restrict__ A, const unsigned short* __restrict__ W,
    const float* __restrict__ bias,
    const float* __restrict__ g1, const float* __restrict__ b1,
    const float* __restrict__ g2, const float* __restrict__ b2,
    float* __restrict__ h, unsigned short* __restrict__ h_bf)
{
    __shared__ unsigned short As[64 * 32];
    __shared__ unsigned short Bs[256 * 32];
    __shared__ float redS[4][64];
    __shared__ float redS2[4][64];
    const int tid = threadIdx.x;
    const int lane = tid & 63, wave = tid >> 6;
    const int quad = lane >> 4, l16 = lane & 15;
    const int wn = wave * 64;
    const int m0 = blockIdx.x * 64;
    f32x4 acc[4][4] = {};
    const int rbase = (lane >> 2);
    const int kk = (lane & 3) * 8;

    for (int k0 = 0; k0 < 256; k0 += 32) {
        {
            int r = wave * 16 + rbase;
            async_copy16(A + (size_t)(m0 + r) * 256 + k0 + kk, &As[wave * 512 + lane * 8]);
        }
#pragma unroll
        for (int c = 0; c < 4; c++) {
            int t = wave * 4 + c;
            int r = t * 16 + rbase;
            async_copy16(W + (size_t)r * 256 + k0 + kk, &Bs[t * 512 + lane * 8]);
        }
        __syncthreads();
        short8 bfr[4];
#pragma unroll
        for (int j = 0; j < 4; j++)
            bfr[j] = *(const short8*)&Bs[(wn + j * 16 + l16) * 32 + quad * 8];
#pragma unroll
        for (int i = 0; i < 4; i++) {
            short8 af = *(const short8*)&As[(i * 16 + l16) * 32 + quad * 8];
#pragma unroll
            for (int j = 0; j < 4; j++)
                acc[i][j] = __builtin_amdgcn_mfma_f32_16x16x32_bf16(af, bfr[j], acc[i][j], 0, 0, 0);
        }
        __syncthreads();
    }

    float bj[4], g1j[4], b1j[4];
#pragma unroll
    for (int j = 0; j < 4; j++) {
        int col = wn + j * 16 + l16;
        bj[j] = bias[col];
        g1j[j] = g1[col]; b1j[j] = b1[col];
    }

#pragma unroll
    for (int i = 0; i < 4; i++)
#pragma unroll
        for (int rg = 0; rg < 4; rg++) {
            int rl = i * 16 + quad * 4 + rg;
#pragma unroll
            for (int j = 0; j < 4; j++) {
                int col = wn + j * 16 + l16;
                acc[i][j][rg] += bj[j] + h[(size_t)(m0 + rl) * 256 + col];
            }
        }
#pragma unroll
    for (int i = 0; i < 4; i++)
#pragma unroll
        for (int rg = 0; rg < 4; rg++) {
            float p = 0.0f, q = 0.0f;
#pragma unroll
            for (int j = 0; j < 4; j++) {
                float v = acc[i][j][rg];
                p += v; q += v * v;
            }
#pragma unroll
            for (int off = 1; off < 16; off <<= 1) {
                p += __shfl_xor(p, off);
                q += __shfl_xor(q, off);
            }
            if (l16 == 0) {
                int rl = i * 16 + quad * 4 + rg;
                redS[wave][rl] = p;
                redS2[wave][rl] = q;
            }
        }
    __syncthreads();
#pragma unroll
    for (int i = 0; i < 4; i++)
#pragma unroll
        for (int rg = 0; rg < 4; rg++) {
            int rl = i * 16 + quad * 4 + rg;
            float s = redS[0][rl] + redS[1][rl] + redS[2][rl] + redS[3][rl];
            float qq = redS2[0][rl] + redS2[1][rl] + redS2[2][rl] + redS2[3][rl];
            float mean = s * (1.0f / 256.0f);
            float rstd = 1.0f / sqrtf(qq * (1.0f / 256.0f) - mean * mean + 1e-5f);
            size_t orow = (size_t)(m0 + rl) * 256;
#pragma unroll
            for (int j = 0; j < 4; j++) {
                int col = wn + j * 16 + l16;
                float y = (acc[i][j][rg] - mean) * rstd * g1j[j] + b1j[j];
                h[orow + col] = y;
                h_bf[orow + col] = f2bf(y);
            }
        }
}

// ================= rel / dist (permuted order) =================
__global__ __launch_bounds__(256) void rel_dist_kernel(
    const float* __restrict__ cur, const int* __restrict__ rowi, const int* __restrict__ coli,
    float* __restrict__ rel, float* __restrict__ dist)
{
    const int e = blockIdx.x * 256 + threadIdx.x;
    int r = rowi[e], c = coli[e];
    float rx = cur[(size_t)r * 3 + 0] - cur[(size_t)c * 3 + 0];
    float ry = cur[(size_t)r * 3 + 1] - cur[(size_t)c * 3 + 1];
    float rz = cur[(size_t)r * 3 + 2] - cur[(size_t)c * 3 + 2];
    rel[(size_t)e * 3 + 0] = rx;
    rel[(size_t)e * 3 + 1] = ry;
    rel[(size_t)e * 3 + 2] = rz;
    float dx = rx + 1e-8f, dy = ry + 1e-8f, dz = rz + 1e-8f;
    dist[e] = sqrtf(dx * dx + dy * dy + dz * dz);
}

__global__ __launch_bounds__(256) void cur_update_kernel(
    float* __restrict__ cur, const float* __restrict__ posupd, const float* __restrict__ ps, int l)
{
    const int i = blockIdx.x * 256 + threadIdx.x;
    cur[i] += ps[l] * posupd[i];
}

// ================= MFMA attention: one block per graph, wave w -> heads {w, w+4} =================
__global__ __launch_bounds__(256) void attn_mfma_kernel(
    const unsigned short* __restrict__ qkv, unsigned short* __restrict__ o)
{
    __shared__ __align__(16) unsigned short pS[4][64 * 72];
    __shared__ __align__(16) unsigned short vtS[4][32 * 72];
    const int g = blockIdx.x;
    const int tid = threadIdx.x;
    const int lane = tid & 63, wave = tid >> 6;
    const int quad = lane >> 4, l16 = lane & 15;
    const unsigned short* base = qkv + (size_t)g * 64 * 768;
    const float scale = 0.17677669529663687f;

    for (int hh = wave; hh < 8; hh += 4) {
        short8 aq[4], bk[4];
#pragma unroll
        for (int i = 0; i < 4; i++)
            aq[i] = *(const short8*)(base + (size_t)(i * 16 + l16) * 768 + hh * 32 + quad * 8);
#pragma unroll
        for (int j = 0; j < 4; j++)
            bk[j] = *(const short8*)(base + (size_t)(j * 16 + l16) * 768 + 256 + hh * 32 + quad * 8);
        {
            const unsigned short* vrow = base + (size_t)lane * 768 + 512 + hh * 32;
#pragma unroll
            for (int d = 0; d < 32; d++)
                vtS[wave][d * 72 + lane] = vrow[d];
        }
        f32x4 sc[4][4];
#pragma unroll
        for (int i = 0; i < 4; i++)
#pragma unroll
            for (int j = 0; j < 4; j++) sc[i][j] = (f32x4){0.f, 0.f, 0.f, 0.f};
#pragma unroll
        for (int i = 0; i < 4; i++)
#pragma unroll
            for (int j = 0; j < 4; j++)
                sc[i][j] = __builtin_amdgcn_mfma_f32_16x16x32_bf16(aq[i], bk[j], sc[i][j], 0, 0, 0);
#pragma unroll
        for (int i = 0; i < 4; i++)
#pragma unroll
            for (int rg = 0; rg < 4; rg++) {
                float v[4];
                float mx = -1e30f;
#pragma unroll
                for (int j = 0; j < 4; j++) {
                    v[j] = sc[i][j][rg] * scale;
                    mx = fmaxf(mx, v[j]);
                }
#pragma unroll
                for (int off = 1; off < 16; off <<= 1) mx = fmaxf(mx, __shfl_xor(mx, off));
                float sum = 0.0f;
#pragma unroll
                for (int j = 0; j < 4; j++) {
                    v[j] = exp_f(v[j] - mx);
                    sum += v[j];
                }
#pragma unroll
                for (int off = 1; off < 16; off <<= 1) sum += __shfl_xor(sum, off);
                float inv = __builtin_amdgcn_rcpf(sum);
                int row = i * 16 + quad * 4 + rg;
#pragma unroll
                for (int j = 0; j < 4; j++)
                    pS[wave][row * 72 + j * 16 + l16] = f2bf(v[j] * inv);
            }
        f32x4 oc[4][2];
#pragma unroll
        for (int i = 0; i < 4; i++)
#pragma unroll
            for (int j = 0; j < 2; j++) oc[i][j] = (f32x4){0.f, 0.f, 0.f, 0.f};
#pragma unroll
        for (int k0 = 0; k0 < 64; k0 += 32) {
            short8 ap[4], bv[2];
#pragma unroll
            for (int i = 0; i < 4; i++)
                ap[i] = *(const short8*)&pS[wave][(i * 16 + l16) * 72 + k0 + quad * 8];
#pragma unroll
            for (int j = 0; j < 2; j++)
                bv[j] = *(const short8*)&vtS[wave][(j * 16 + l16) * 72 + k0 + quad * 8];
#pragma unroll
            for (int i = 0; i < 4; i++)
#pragma unroll
                for (int j = 0; j < 2; j++)
                    oc[i][j] = __builtin_amdgcn_mfma_f32_16x16x32_bf16(ap[i], bv[j], oc[i][j], 0, 0, 0);
        }
#pragma unroll
        for (int i = 0; i < 4; i++)
#pragma unroll
            for (int rg = 0; rg < 4; rg++) {
                int row = i * 16 + quad * 4 + rg;
                unsigned short* ob = o + (size_t)(g * 64 + row) * 256 + hh * 32;
#pragma unroll
                for (int j = 0; j < 2; j++)
                    ob[j * 16 + l16] = f2bf(oc[i][j][rg]);
            }
    }
}

extern "C" void kernel_launch(void* const* d_in, const int* in_sizes, int n_in,
                              void* d_out, int out_size, void* d_ws, size_t ws_size,
                              hipStream_t stream)
{
    const float* x    = (const float*)d_in[0];
    const float* pos  = (const float*)d_in[1];
    const int*   ei   = (const int*)d_in[2];
    const float* pe_w1 = (const float*)d_in[5];
    const float* pe_b1 = (const float*)d_in[6];
    const float* pe_w2 = (const float*)d_in[7];
    const float* pe_b2 = (const float*)d_in[8];
    const float* pe_lg = (const float*)d_in[9];
    const float* pe_lb = (const float*)d_in[10];
    const float* ph_w1 = (const float*)d_in[11];
    const float* ph_b1 = (const float*)d_in[12];
    const float* ph_w2 = (const float*)d_in[13];
    const float* ph_b2 = (const float*)d_in[14];
    const float* ph_lg = (const float*)d_in[15];
    const float* ph_lb = (const float*)d_in[16];
    const float* px_w1 = (const float*)d_in[17];
    const float* px_b1 = (const float*)d_in[18];
    const float* px_w2 = (const float*)d_in[19];
    const float* px_b2 = (const float*)d_in[20];
    const float* ain_w = (const float*)d_in[21];
    const float* ain_b = (const float*)d_in[22];
    const float* aout_w = (const float*)d_in[23];
    const float* aout_b = (const float*)d_in[24];
    const float* lnh_g = (const float*)d_in[25];
    const float* lnh_b = (const float*)d_in[26];
    const float* lna_g = (const float*)d_in[27];
    const float* lna_b = (const float*)d_in[28];
    const float* ff_w1 = (const float*)d_in[29];
    const float* ff_b1 = (const float*)d_in[30];
    const float* ff_w2 = (const float*)d_in[31];
    const float* ff_b2 = (const float*)d_in[32];
    const float* ps    = (const float*)d_in[33];

    char* p = (char*)d_ws;
    auto alloc = [&](size_t bytes) { char* r = p; p += (bytes + 63) & ~(size_t)63; return r; };
    float* h      = (float*)alloc((size_t)NTOTC * HC * 4);
    unsigned short* h_bf  = (unsigned short*)alloc((size_t)NTOTC * HC * 2);
    unsigned short* xcat_bf = (unsigned short*)alloc((size_t)NTOTC * 512 * 2);
    float* cur    = (float*)alloc((size_t)NTOTC * 3 * 4);
    float* relP   = (float*)alloc((size_t)NEDGEC * 3 * 4);
    float* distP  = (float*)alloc((size_t)NEDGEC * 4);
    float* posupd = (float*)alloc((size_t)NTOTC * 3 * 4);
    float* hmsg   = (float*)alloc((size_t)NTOTC * HC * 4);
    unsigned short* qkv_bf = (unsigned short*)alloc((size_t)NTOTC * 3 * HC * 2);
    unsigned short* o_bf   = (unsigned short*)alloc((size_t)NTOTC * HC * 2);
    unsigned short* ff1_bf = (unsigned short*)alloc((size_t)NTOTC * 4 * HC * 2);
    int* cnt  = (int*)alloc(16384 * 4);
    int* ptrw = (int*)alloc(16384 * 4);
    int* rowP = (int*)alloc((size_t)NEDGEC * 4);
    int* colP = (int*)alloc((size_t)NEDGEC * 4);
    float* zbias = (float*)alloc(512 * 4);
    unsigned short* w_pe1s = (unsigned short*)alloc((size_t)LC * 512 * 256 * 2);
    float*          w_last = (float*)alloc((size_t)LC * 256 * 4);
    unsigned short* w_pe2  = (unsigned short*)alloc((size_t)LC * 256 * 256 * 2);
    unsigned short* w_ph1  = (unsigned short*)alloc((size_t)LC * 256 * 256 * 2);
    unsigned short* w_ph2  = (unsigned short*)alloc((size_t)LC * 256 * 256 * 2);
    unsigned short* w_px1  = (unsigned short*)alloc((size_t)LC * 256 * 256 * 2);
    unsigned short* w_ain  = (unsigned short*)alloc((size_t)LC * 768 * 256 * 2);
    unsigned short* w_aout = (unsigned short*)alloc((size_t)LC * 256 * 256 * 2);
    unsigned short* w_ff1  = (unsigned short*)alloc((size_t)LC * 1024 * 256 * 2);
    unsigned short* w_ff2  = (unsigned short*)alloc((size_t)LC * 256 * 1024 * 2);

    // ---- counting sort of edges by col ----
    hipMemsetAsync(cnt, 0, 16384 * 4, stream);
    hipMemsetAsync(zbias, 0, 512 * 4, stream);
    hist_kernel<<<NEDGEC / 256, 256, 0, stream>>>(ei + NEDGEC, cnt);
    scan16k_kernel<<<1, 256, 0, stream>>>(cnt, ptrw);
    permute_kernel<<<NEDGEC / 256, 256, 0, stream>>>(ei, ei + NEDGEC, ptrw, rowP, colP);

    // ---- convert weights to bf16 ----
    conv_pe1_kernel<<<(LC * 256 * 513 + 255) / 256, 256, 0, stream>>>(pe_w1, w_pe1s, w_last);
    conv_bf16_kernel<<<1536, 256, 0, stream>>>(pe_w2, w_pe2, LC * 256 * 256);
    conv_bf16_kernel<<<1536, 256, 0, stream>>>(ph_w1, w_ph1, LC * 256 * 256);
    conv_bf16_kernel<<<1536, 256, 0, stream>>>(ph_w2, w_ph2, LC * 256 * 256);
    conv_bf16_kernel<<<1536, 256, 0, stream>>>(px_w1, w_px1, LC * 256 * 256);
    conv_bf16_kernel<<<4608, 256, 0, stream>>>(ain_w, w_ain, LC * 768 * 256);
    conv_bf16_kernel<<<1536, 256, 0, stream>>>(aout_w, w_aout, LC * 256 * 256);
    conv_bf16_kernel<<<6144, 256, 0, stream>>>(ff_w1, w_ff1, LC * 1024 * 256);
    conv_bf16_kernel<<<6144, 256, 0, stream>>>(ff_w2, w_ff2, LC * 256 * 1024);

    hipMemcpyAsync(h, x, (size_t)NTOTC * HC * 4, hipMemcpyDeviceToDevice, stream);
    hipMemcpyAsync(cur, pos, (size_t)NTOTC * 3 * 4, hipMemcpyDeviceToDevice, stream);
    conv_bf16_kernel<<<4096, 256, 0, stream>>>(x, h_bf, NTOTC * HC);

    for (int l = 0; l < LC; l++) {
        rel_dist_kernel<<<NEDGEC / 256, 256, 0, stream>>>(cur, rowP, colP, relP, distP);
        hipMemsetAsync(hmsg, 0, (size_t)NTOTC * HC * 4, stream);
        hipMemsetAsync(posupd, 0, (size_t)NTOTC * 3 * 4, stream);

        // xcat = h @ [W1a;W1b]^T
        mgemm_kernel<0, false, false, true><<<dim3(NTOTC / 128, 4), 256, 0, stream>>>(
            h_bf, w_pe1s + (size_t)l * 512 * 256, zbias,
            nullptr, nullptr, xcat_bf, NTOTC, 512, HC);

        fused_edge_kernel<<<NEDGEC / 128, 256, 0, stream>>>(
            xcat_bf, rowP, colP, distP, relP,
            w_last + (size_t)l * 256, pe_b1 + (size_t)l * HC,
            w_pe2 + (size_t)l * 256 * 256, pe_b2 + (size_t)l * HC,
            pe_lg + (size_t)l * HC, pe_lb + (size_t)l * HC,
            w_px1 + (size_t)l * 256 * 256, px_b1 + (size_t)l * HC,
            px_w2 + (size_t)l * HC, px_b2 + l,
            hmsg, posupd);

        // phi_h fully fused
        phi_h_fused_kernel<<<NTOTC / 64, 256, 0, stream>>>(
            h, hmsg,
            w_ph1 + (size_t)l * 256 * 256, ph_b1 + (size_t)l * HC,
            w_ph2 + (size_t)l * 256 * 256, ph_b2 + (size_t)l * HC,
            ph_lg + (size_t)l * HC, ph_lb + (size_t)l * HC,
            lnh_g + (size_t)l * HC, lnh_b + (size_t)l * HC, h, h_bf);
        cur_update_kernel<<<(NTOTC * 3) / 256, 256, 0, stream>>>(cur, posupd, ps, l);

        // attention
        mgemm_kernel<0, false, false, true><<<dim3(NTOTC / 128, 6), 256, 0, stream>>>(
            h_bf, w_ain + (size_t)l * 768 * 256, ain_b + (size_t)l * 3 * HC,
            nullptr, nullptr, qkv_bf, NTOTC, 3 * HC, HC);
        attn_mfma_kernel<<<NTOTC / 64, 256, 0, stream>>>(qkv_bf, o_bf);
        node_fused_kernel<false><<<NTOTC / 64, 256, 0, stream>>>(
            o_bf, w_aout + (size_t)l * 256 * 256, aout_b + (size_t)l * HC,
            lna_g + (size_t)l * HC, lna_b + (size_t)l * HC,
            nullptr, nullptr, h, h_bf);

        // feed-forward with residual
        mgemm_kernel<2, false, false, true><<<dim3(NTOTC / 128, 8), 256, 0, stream>>>(
            h_bf, w_ff1 + (size_t)l * 1024 * 256, ff_b1 + (size_t)l * 4 * HC,
            nullptr, nullptr, ff1_bf, NTOTC, 4 * HC, HC);
        mgemm_kernel<0, true, true, true><<<dim3(NTOTC / 128, 2), 256, 0, stream>>>(
            ff1_bf, w_ff2 + (size_t)l * 256 * 1024, ff_b2 + (size_t)l * HC,
            h, h, h_bf, NTOTC, HC, 4 * HC);
    }

    hipMemcpyAsync(d_out, h, (size_t)NTOTC * HC * 4, hipMemcpyDeviceToDevice, stream);
    hipMemcpyAsync((float*)d_out + (size_t)NTOTC * HC, cur, (size_t)NTOTC * 3 * 4,
                   hipMemcpyDeviceToDevice, stream);
}

// Round 11
// 2395.847 us; speedup vs baseline: 1.0903x; 1.0903x over previous
//
#include <hip/hip_runtime.h>
#include <cstddef>
#include <cstdint>

#define NTOTC 16384
#define HC 256
#define LC 6
#define NEDGEC 262144
#define NHEADSC 8

typedef __attribute__((ext_vector_type(8))) short short8;
typedef __attribute__((ext_vector_type(4))) float f32x4;

__device__ __forceinline__ unsigned short f2bf(float f) {
    unsigned int u = __float_as_uint(f);
    u += 0x7fff + ((u >> 16) & 1);   // round-to-nearest-even
    return (unsigned short)(u >> 16);
}
__device__ __forceinline__ float bf2f(unsigned short s) {
    return __uint_as_float(((unsigned int)s) << 16);
}
__device__ __forceinline__ void async_copy16(const void* g, void* l) {
    __builtin_amdgcn_global_load_lds(
        (const __attribute__((address_space(1))) unsigned int*)g,
        (__attribute__((address_space(3))) unsigned int*)l, 16, 0, 0);
}
// fast transcendentals; ~1e-6 rel err, negligible vs bf16
__device__ __forceinline__ float exp_f(float v) {
    return __builtin_amdgcn_exp2f(v * 1.4426950408889634f);
}
__device__ __forceinline__ float silu_f(float v) {
    return v * __builtin_amdgcn_rcpf(1.0f + __builtin_amdgcn_exp2f(-v * 1.4426950408889634f));
}
__device__ __forceinline__ float tanh_f(float v) {
    float e = __builtin_amdgcn_exp2f(v * 2.8853900817779268f);   // e^(2v)
    return 1.0f - 2.0f * __builtin_amdgcn_rcpf(1.0f + e);
}

// ================= weight conversion =================
__global__ __launch_bounds__(256) void conv_bf16_kernel(
    const float* __restrict__ in, unsigned short* __restrict__ out, int n)
{
    for (int i = blockIdx.x * 256 + threadIdx.x; i < n; i += gridDim.x * 256)
        out[i] = f2bf(in[i]);
}

// phi_e_w1 [L,256,513] -> stacked bf16 [L,512,256] ([W1a;W1b]) + fp32 dist column [L,256]
__global__ __launch_bounds__(256) void conv_pe1_kernel(
    const float* __restrict__ in, unsigned short* __restrict__ outk, float* __restrict__ wlast)
{
    int idx = blockIdx.x * 256 + threadIdx.x;
    if (idx >= LC * 256 * 513) return;
    int l = idx / (256 * 513);
    int rem = idx % (256 * 513);
    int n = rem / 513;
    int k = rem % 513;
    float v = in[idx];
    if (k == 512) wlast[l * 256 + n] = v;
    else if (k < 256) outk[(size_t)l * 512 * 256 + (size_t)n * 256 + k] = f2bf(v);
    else outk[(size_t)l * 512 * 256 + (size_t)(256 + n) * 256 + (k - 256)] = f2bf(v);
}

// ================= counting sort of edges by col =================
__global__ __launch_bounds__(256) void hist_kernel(
    const int* __restrict__ col, int* __restrict__ cnt)
{
    int e = blockIdx.x * 256 + threadIdx.x;
    atomicAdd(&cnt[col[e]], 1);
}

__global__ __launch_bounds__(256) void scan16k_kernel(
    const int* __restrict__ cnt, int* __restrict__ ptrw)
{
    __shared__ int partial[256];
    const int t = threadIdx.x;
    const int base = t * 64;
    int loc[64];
    int s = 0;
#pragma unroll
    for (int i = 0; i < 64; i++) { loc[i] = s; s += cnt[base + i]; }
    partial[t] = s;
    __syncthreads();
    if (t == 0) {
        int run = 0;
        for (int i = 0; i < 256; i++) { int tmp = partial[i]; partial[i] = run; run += tmp; }
    }
    __syncthreads();
    int off = partial[t];
#pragma unroll
    for (int i = 0; i < 64; i++) ptrw[base + i] = off + loc[i];
}

__global__ __launch_bounds__(256) void permute_kernel(
    const int* __restrict__ row, const int* __restrict__ col, int* __restrict__ ptrw,
    int* __restrict__ rowP, int* __restrict__ colP)
{
    int e = blockIdx.x * 256 + threadIdx.x;
    int c = col[e];
    int pos = atomicAdd(&ptrw[c], 1);
    rowP[pos] = row[e];
    colP[pos] = c;
}

// ================= generic MFMA GEMM: C = act(A @ W^T + bias)(+R) =================
template<int ACT, bool RES, bool WF, bool WB>
__global__ __launch_bounds__(256) void mgemm_kernel(
    const unsigned short* __restrict__ A, const unsigned short* __restrict__ W,
    const float* __restrict__ bias, const float* __restrict__ R,
    float* __restrict__ Cf, unsigned short* __restrict__ Cb,
    int M, int N, int K)
{
    __shared__ unsigned short As[128 * 32];
    __shared__ unsigned short Bs[128 * 32];
    const int tid = threadIdx.x;
    const int lane = tid & 63, wave = tid >> 6;
    const int quad = lane >> 4, l16 = lane & 15;
    const int wm = (wave >> 1) * 64, wn = (wave & 1) * 64;
    const int m0 = blockIdx.x * 128, n0 = blockIdx.y * 128;
    f32x4 acc[4][4] = {};
    const int rbase = (lane >> 2);
    const int kk = (lane & 3) * 8;

    for (int k0 = 0; k0 < K; k0 += 32) {
#pragma unroll
        for (int c = 0; c < 2; c++) {
            int t = wave * 2 + c;
            int r = t * 16 + rbase;
            async_copy16(A + (size_t)(m0 + r) * K + k0 + kk, &As[t * 512 + lane * 8]);
            async_copy16(W + (size_t)(n0 + r) * K + k0 + kk, &Bs[t * 512 + lane * 8]);
        }
        __syncthreads();
        short8 af[4], bfr[4];
#pragma unroll
        for (int i = 0; i < 4; i++)
            af[i] = *(const short8*)&As[(wm + i * 16 + l16) * 32 + quad * 8];
#pragma unroll
        for (int j = 0; j < 4; j++)
            bfr[j] = *(const short8*)&Bs[(wn + j * 16 + l16) * 32 + quad * 8];
#pragma unroll
        for (int i = 0; i < 4; i++)
#pragma unroll
            for (int j = 0; j < 4; j++)
                acc[i][j] = __builtin_amdgcn_mfma_f32_16x16x32_bf16(af[i], bfr[j], acc[i][j], 0, 0, 0);
        __syncthreads();
    }
#pragma unroll
    for (int j = 0; j < 4; j++) {
        int col = n0 + wn + j * 16 + l16;
        float bi = bias[col];
#pragma unroll
        for (int i = 0; i < 4; i++) {
#pragma unroll
            for (int rg = 0; rg < 4; rg++) {
                int row = m0 + wm + i * 16 + quad * 4 + rg;
                float v = acc[i][j][rg] + bi;
                if (ACT == 1) v = silu_f(v);
                if (ACT == 2) v = 0.5f * v * (1.0f + erff(v * 0.7071067811865476f));
                if (RES) v += R[(size_t)row * N + col];
                if (WF) Cf[(size_t)row * N + col] = v;
                if (WB) Cb[(size_t)row * N + col] = f2bf(v);
            }
        }
    }
}

// ================= FUSED edge pipeline (M=64, rel/dist inline) =================
__global__ __launch_bounds__(256, 4) void fused_edge_kernel(
    const unsigned short* __restrict__ xcat, const float* __restrict__ cur,
    const int* __restrict__ rowP, const int* __restrict__ colP,
    const float* __restrict__ wlast, const float* __restrict__ b1,
    const unsigned short* __restrict__ W2, const float* __restrict__ b2,
    const float* __restrict__ lg, const float* __restrict__ lb,
    const unsigned short* __restrict__ W3, const float* __restrict__ b3,
    const float* __restrict__ w2v, const float* __restrict__ b2s,
    float* __restrict__ hmsg, float* __restrict__ posupd)
{
    __shared__ __align__(16) unsigned short tS[64 * 264];
    __shared__ float redS[4][64];
    __shared__ float redS2[4][64];
    __shared__ int rowS[64], colS[64], flagS[64];
    __shared__ float distS[64];
    __shared__ float relS[64][3];
    __shared__ float cfS[64];

    const int tid = threadIdx.x;
    const int lane = tid & 63, wave = tid >> 6;
    const int quad = lane >> 4, l16 = lane & 15;
    const int wn = wave * 64;
    const int m0 = blockIdx.x * 64;

    if (tid < 64) {
        int r = rowP[m0 + tid];
        int c = colP[m0 + tid];
        rowS[tid] = r;
        colS[tid] = c;
        float rx = cur[(size_t)r * 3 + 0] - cur[(size_t)c * 3 + 0];
        float ry = cur[(size_t)r * 3 + 1] - cur[(size_t)c * 3 + 1];
        float rz = cur[(size_t)r * 3 + 2] - cur[(size_t)c * 3 + 2];
        relS[tid][0] = rx;
        relS[tid][1] = ry;
        relS[tid][2] = rz;
        float dx = rx + 1e-8f, dy = ry + 1e-8f, dz = rz + 1e-8f;  // ref adds eps per component
        distS[tid] = sqrtf(dx * dx + dy * dy + dz * dz);
    }
    __syncthreads();
    if (tid < 64) flagS[tid] = (tid == 63) || (colS[tid] != colS[tid + 1]);

    // ---- Stage 1: gather-add replacing edge GEMM1 ----
    {
        const int cb = lane * 4;
        float4 wl4 = *(const float4*)&wlast[cb];
        float4 b14 = *(const float4*)&b1[cb];
#pragma unroll
        for (int rr = 0; rr < 16; rr++) {
            int r = rr * 4 + wave;
            const ushort4 ua = *(const ushort4*)(xcat + (size_t)rowS[r] * 512 + cb);
            const ushort4 ub = *(const ushort4*)(xcat + (size_t)colS[r] * 512 + 256 + cb);
            float dv = distS[r];
            float v0 = bf2f(ua.x) + bf2f(ub.x) + dv * wl4.x + b14.x;
            float v1 = bf2f(ua.y) + bf2f(ub.y) + dv * wl4.y + b14.y;
            float v2 = bf2f(ua.z) + bf2f(ub.z) + dv * wl4.z + b14.z;
            float v3 = bf2f(ua.w) + bf2f(ub.w) + dv * wl4.w + b14.w;
            ushort4 o;
            o.x = f2bf(silu_f(v0));
            o.y = f2bf(silu_f(v1));
            o.z = f2bf(silu_f(v2));
            o.w = f2bf(silu_f(v3));
            *(ushort4*)&tS[r * 264 + cb] = o;
        }
    }
    __syncthreads();

    f32x4 acc[4][4];

    // ---- GEMM2: K=256, A from tS, W2 direct; NO barriers in k-loop ----
#pragma unroll
    for (int i = 0; i < 4; i++)
#pragma unroll
        for (int j = 0; j < 4; j++) acc[i][j] = (f32x4){0.f, 0.f, 0.f, 0.f};
#pragma unroll
    for (int k0 = 0; k0 < 256; k0 += 32) {
        short8 af[4], bfr[4];
#pragma unroll
        for (int j = 0; j < 4; j++)
            bfr[j] = *(const short8*)(W2 + (size_t)(wn + j * 16 + l16) * 256 + k0 + quad * 8);
#pragma unroll
        for (int i = 0; i < 4; i++)
            af[i] = *(const short8*)&tS[(i * 16 + l16) * 264 + k0 + quad * 8];
#pragma unroll
        for (int i = 0; i < 4; i++)
#pragma unroll
            for (int j = 0; j < 4; j++)
                acc[i][j] = __builtin_amdgcn_mfma_f32_16x16x32_bf16(af[i], bfr[j], acc[i][j], 0, 0, 0);
    }
    __syncthreads();
    // epilogue 2: LN -> m -> tS (overwrite)
    {
        float b2j[4], gj[4], bbj[4];
#pragma unroll
        for (int j = 0; j < 4; j++) {
            int col = wn + j * 16 + l16;
            b2j[j] = b2[col];
            gj[j] = lg[col];
            bbj[j] = lb[col];
        }
#pragma unroll
        for (int i = 0; i < 4; i++)
#pragma unroll
            for (int rg = 0; rg < 4; rg++) {
                float p = 0.0f, q = 0.0f;
#pragma unroll
                for (int j = 0; j < 4; j++) {
                    float v = acc[i][j][rg] + b2j[j];
                    p += v; q += v * v;
                }
#pragma unroll
                for (int off = 1; off < 16; off <<= 1) {
                    p += __shfl_xor(p, off);
                    q += __shfl_xor(q, off);
                }
                if (l16 == 0) {
                    int row = i * 16 + quad * 4 + rg;
                    redS[wave][row] = p;
                    redS2[wave][row] = q;
                }
            }
        __syncthreads();
#pragma unroll
        for (int i = 0; i < 4; i++)
#pragma unroll
            for (int rg = 0; rg < 4; rg++) {
                int row = i * 16 + quad * 4 + rg;
                float s = redS[0][row] + redS[1][row] + redS[2][row] + redS[3][row];
                float qq = redS2[0][row] + redS2[1][row] + redS2[2][row] + redS2[3][row];
                float mean = s * (1.0f / 256.0f);
                float rstd = 1.0f / sqrtf(qq * (1.0f / 256.0f) - mean * mean + 1e-5f);
#pragma unroll
                for (int j = 0; j < 4; j++) {
                    int col = wn + j * 16 + l16;
                    float v = acc[i][j][rg] + b2j[j];
                    tS[row * 264 + col] = f2bf((v - mean) * rstd * gj[j] + bbj[j]);
                }
            }
    }
    __syncthreads();

    // ---- segmented scatter of m into hmsg ----
    {
        const int c = tid;
        float s = 0.0f;
#pragma unroll
        for (int r = 0; r < 64; r++) {
            s += bf2f(tS[r * 264 + c]);
            if (flagS[r]) {
                atomicAdd(&hmsg[(size_t)colS[r] * 256 + c], s);
                s = 0.0f;
            }
        }
    }

    // ---- GEMM3: K=256, A = m from tS, W3 direct ----
#pragma unroll
    for (int i = 0; i < 4; i++)
#pragma unroll
        for (int j = 0; j < 4; j++) acc[i][j] = (f32x4){0.f, 0.f, 0.f, 0.f};
#pragma unroll
    for (int k0 = 0; k0 < 256; k0 += 32) {
        short8 af[4], bfr[4];
#pragma unroll
        for (int j = 0; j < 4; j++)
            bfr[j] = *(const short8*)(W3 + (size_t)(wn + j * 16 + l16) * 256 + k0 + quad * 8);
#pragma unroll
        for (int i = 0; i < 4; i++)
            af[i] = *(const short8*)&tS[(i * 16 + l16) * 264 + k0 + quad * 8];
#pragma unroll
        for (int i = 0; i < 4; i++)
#pragma unroll
            for (int j = 0; j < 4; j++)
                acc[i][j] = __builtin_amdgcn_mfma_f32_16x16x32_bf16(af[i], bfr[j], acc[i][j], 0, 0, 0);
    }
    // epilogue 3
    {
        float b3j[4], w2j[4];
#pragma unroll
        for (int j = 0; j < 4; j++) {
            int col = wn + j * 16 + l16;
            b3j[j] = b3[col];
            w2j[j] = w2v[col];
        }
#pragma unroll
        for (int i = 0; i < 4; i++)
#pragma unroll
            for (int rg = 0; rg < 4; rg++) {
                float p = 0.0f;
#pragma unroll
                for (int j = 0; j < 4; j++)
                    p += silu_f(acc[i][j][rg] + b3j[j]) * w2j[j];
#pragma unroll
                for (int off = 1; off < 16; off <<= 1) p += __shfl_xor(p, off);
                if (l16 == 0) redS[wave][i * 16 + quad * 4 + rg] = p;
            }
        __syncthreads();
        if (tid < 64) {
            float tot = redS[0][tid] + redS[1][tid] + redS[2][tid] + redS[3][tid] + b2s[0];
            cfS[tid] = tanh_f(tot);
        }
        __syncthreads();
        if (tid < 3) {
            const int comp = tid;
            float s = 0.0f;
#pragma unroll
            for (int r = 0; r < 64; r++) {
                s += relS[r][comp] * cfS[r];
                if (flagS[r]) {
                    atomicAdd(&posupd[(size_t)colS[r] * 3 + comp], s);
                    s = 0.0f;
                }
            }
        }
    }
}

// ============ phi_h fused: h = LN2(h + LN1(silu((h+hmsg)@W1^T+b1)@W2^T+b2)) ============
__global__ __launch_bounds__(256) void phi_h_fused_kernel(
    const float* __restrict__ h_in, const float* __restrict__ hmsg,
    const unsigned short* __restrict__ W1, const float* __restrict__ b1v,
    const unsigned short* __restrict__ W2, const float* __restrict__ bias,
    const float* __restrict__ g1, const float* __restrict__ bb1,
    const float* __restrict__ g2, const float* __restrict__ bb2,
    float* __restrict__ h, unsigned short* __restrict__ h_bf)
{
    __shared__ __align__(16) unsigned short As[64 * 32];
    __shared__ __align__(16) unsigned short Bs[256 * 32];
    __shared__ __align__(16) unsigned short tS[64 * 264];
    __shared__ float redS[4][64];
    __shared__ float redS2[4][64];
    const int tid = threadIdx.x;
    const int lane = tid & 63, wave = tid >> 6;
    const int quad = lane >> 4, l16 = lane & 15;
    const int wn = wave * 64;
    const int m0 = blockIdx.x * 64;
    f32x4 acc[4][4] = {};
    const int rbase = (lane >> 2);
    const int kk = (lane & 3) * 8;

    for (int k0 = 0; k0 < 256; k0 += 32) {
#pragma unroll
        for (int c = 0; c < 2; c++) {
            int u = c * 256 + tid;
            int r = u >> 3, kg = (u & 7) * 4;
            float4 a = *(const float4*)&h_in[(size_t)(m0 + r) * 256 + k0 + kg];
            float4 b = *(const float4*)&hmsg[(size_t)(m0 + r) * 256 + k0 + kg];
            ushort4 o4;
            o4.x = f2bf(a.x + b.x);
            o4.y = f2bf(a.y + b.y);
            o4.z = f2bf(a.z + b.z);
            o4.w = f2bf(a.w + b.w);
            *(ushort4*)&As[r * 32 + kg] = o4;
        }
#pragma unroll
        for (int c = 0; c < 4; c++) {
            int t = wave * 4 + c;
            int r = t * 16 + rbase;
            async_copy16(W1 + (size_t)r * 256 + k0 + kk, &Bs[t * 512 + lane * 8]);
        }
        __syncthreads();
        short8 bfr[4];
#pragma unroll
        for (int j = 0; j < 4; j++)
            bfr[j] = *(const short8*)&Bs[(wn + j * 16 + l16) * 32 + quad * 8];
#pragma unroll
        for (int i = 0; i < 4; i++) {
            short8 af = *(const short8*)&As[(i * 16 + l16) * 32 + quad * 8];
#pragma unroll
            for (int j = 0; j < 4; j++)
                acc[i][j] = __builtin_amdgcn_mfma_f32_16x16x32_bf16(af, bfr[j], acc[i][j], 0, 0, 0);
        }
        __syncthreads();
    }
    {
        float b1j[4];
#pragma unroll
        for (int j = 0; j < 4; j++) b1j[j] = b1v[wn + j * 16 + l16];
#pragma unroll
        for (int i = 0; i < 4; i++)
#pragma unroll
            for (int rg = 0; rg < 4; rg++) {
                int row = i * 16 + quad * 4 + rg;
#pragma unroll
                for (int j = 0; j < 4; j++) {
                    int col = wn + j * 16 + l16;
                    tS[row * 264 + col] = f2bf(silu_f(acc[i][j][rg] + b1j[j]));
                }
            }
    }
    __syncthreads();

#pragma unroll
    for (int i = 0; i < 4; i++)
#pragma unroll
        for (int j = 0; j < 4; j++) acc[i][j] = (f32x4){0.f, 0.f, 0.f, 0.f};
#pragma unroll
    for (int k0 = 0; k0 < 256; k0 += 32) {
        short8 af[4], bfr[4];
#pragma unroll
        for (int j = 0; j < 4; j++)
            bfr[j] = *(const short8*)(W2 + (size_t)(wn + j * 16 + l16) * 256 + k0 + quad * 8);
#pragma unroll
        for (int i = 0; i < 4; i++)
            af[i] = *(const short8*)&tS[(i * 16 + l16) * 264 + k0 + quad * 8];
#pragma unroll
        for (int i = 0; i < 4; i++)
#pragma unroll
            for (int j = 0; j < 4; j++)
                acc[i][j] = __builtin_amdgcn_mfma_f32_16x16x32_bf16(af[i], bfr[j], acc[i][j], 0, 0, 0);
    }

    float bj[4], g1j[4], b1j[4], g2j[4], b2j[4];
#pragma unroll
    for (int j = 0; j < 4; j++) {
        int col = wn + j * 16 + l16;
        bj[j] = bias[col];
        g1j[j] = g1[col]; b1j[j] = bb1[col];
        g2j[j] = g2[col]; b2j[j] = bb2[col];
    }
#pragma unroll
    for (int i = 0; i < 4; i++)
#pragma unroll
        for (int rg = 0; rg < 4; rg++) {
            float p = 0.0f, q = 0.0f;
#pragma unroll
            for (int j = 0; j < 4; j++) {
                float v = acc[i][j][rg] + bj[j];
                p += v; q += v * v;
            }
#pragma unroll
            for (int off = 1; off < 16; off <<= 1) {
                p += __shfl_xor(p, off);
                q += __shfl_xor(q, off);
            }
            if (l16 == 0) {
                int rl = i * 16 + quad * 4 + rg;
                redS[wave][rl] = p;
                redS2[wave][rl] = q;
            }
        }
    __syncthreads();
#pragma unroll
    for (int i = 0; i < 4; i++)
#pragma unroll
        for (int rg = 0; rg < 4; rg++) {
            int rl = i * 16 + quad * 4 + rg;
            float s = redS[0][rl] + redS[1][rl] + redS[2][rl] + redS[3][rl];
            float qq = redS2[0][rl] + redS2[1][rl] + redS2[2][rl] + redS2[3][rl];
            float mean = s * (1.0f / 256.0f);
            float rstd = 1.0f / sqrtf(qq * (1.0f / 256.0f) - mean * mean + 1e-5f);
#pragma unroll
            for (int j = 0; j < 4; j++) {
                int col = wn + j * 16 + l16;
                float v = acc[i][j][rg] + bj[j];
                float hu = (v - mean) * rstd * g1j[j] + b1j[j];
                acc[i][j][rg] = hu + h_in[(size_t)(m0 + rl) * 256 + col];
            }
        }
    __syncthreads();
#pragma unroll
    for (int i = 0; i < 4; i++)
#pragma unroll
        for (int rg = 0; rg < 4; rg++) {
            float p = 0.0f, q = 0.0f;
#pragma unroll
            for (int j = 0; j < 4; j++) {
                float v = acc[i][j][rg];
                p += v; q += v * v;
            }
#pragma unroll
            for (int off = 1; off < 16; off <<= 1) {
                p += __shfl_xor(p, off);
                q += __shfl_xor(q, off);
            }
            if (l16 == 0) {
                int rl = i * 16 + quad * 4 + rg;
                redS[wave][rl] = p;
                redS2[wave][rl] = q;
            }
        }
    __syncthreads();
#pragma unroll
    for (int i = 0; i < 4; i++)
#pragma unroll
        for (int rg = 0; rg < 4; rg++) {
            int rl = i * 16 + quad * 4 + rg;
            float s = redS[0][rl] + redS[1][rl] + redS[2][rl] + redS[3][rl];
            float qq = redS2[0][rl] + redS2[1][rl] + redS2[2][rl] + redS2[3][rl];
            float mean = s * (1.0f / 256.0f);
            float rstd = 1.0f / sqrtf(qq * (1.0f / 256.0f) - mean * mean + 1e-5f);
            size_t orow = (size_t)(m0 + rl) * 256;
#pragma unroll
            for (int j = 0; j < 4; j++) {
                int col = wn + j * 16 + l16;
                float y = (acc[i][j][rg] - mean) * rstd * g2j[j] + b2j[j];
                h[orow + col] = y;
                h_bf[orow + col] = f2bf(y);
            }
        }
}

// ============ fused node GEMM + LN epilogue (attn-out path) ============
template<bool LN2>
__global__ __launch_bounds__(256) void node_fused_kernel(
    const unsigned short* __restrict__ A, const unsigned short* __restrict__ W,
    const float* __restrict__ bias,
    const float* __restrict__ g1, const float* __restrict__ b1,
    const float* __restrict__ g2, const float* __restrict__ b2,
    float* __restrict__ h, unsigned short* __restrict__ h_bf)
{
    __shared__ unsigned short As[64 * 32];
    __shared__ unsigned short Bs[256 * 32];
    __shared__ float redS[4][64];
    __shared__ float redS2[4][64];
    const int tid = threadIdx.x;
    const int lane = tid & 63, wave = tid >> 6;
    const int quad = lane >> 4, l16 = lane & 15;
    const int wn = wave * 64;
    const int m0 = blockIdx.x * 64;
    f32x4 acc[4][4] = {};
    const int rbase = (lane >> 2);
    const int kk = (lane & 3) * 8;

    for (int k0 = 0; k0 < 256; k0 += 32) {
        {
            int r = wave * 16 + rbase;
            async_copy16(A + (size_t)(m0 + r) * 256 + k0 + kk, &As[wave * 512 + lane * 8]);
        }
#pragma unroll
        for (int c = 0; c < 4; c++) {
            int t = wave * 4 + c;
            int r = t * 16 + rbase;
            async_copy16(W + (size_t)r * 256 + k0 + kk, &Bs[t * 512 + lane * 8]);
        }
        __syncthreads();
        short8 bfr[4];
#pragma unroll
        for (int j = 0; j < 4; j++)
            bfr[j] = *(const short8*)&Bs[(wn + j * 16 + l16) * 32 + quad * 8];
#pragma unroll
        for (int i = 0; i < 4; i++) {
            short8 af = *(const short8*)&As[(i * 16 + l16) * 32 + quad * 8];
#pragma unroll
            for (int j = 0; j < 4; j++)
                acc[i][j] = __builtin_amdgcn_mfma_f32_16x16x32_bf16(af, bfr[j], acc[i][j], 0, 0, 0);
        }
        __syncthreads();
    }

    float bj[4], g1j[4], b1j[4];
#pragma unroll
    for (int j = 0; j < 4; j++) {
        int col = wn + j * 16 + l16;
        bj[j] = bias[col];
        g1j[j] = g1[col]; b1j[j] = b1[col];
    }

#pragma unroll
    for (int i = 0; i < 4; i++)
#pragma unroll
        for (int rg = 0; rg < 4; rg++) {
            int rl = i * 16 + quad * 4 + rg;
#pragma unroll
            for (int j = 0; j < 4; j++) {
                int col = wn + j * 16 + l16;
                acc[i][j][rg] += bj[j] + h[(size_t)(m0 + rl) * 256 + col];
            }
        }
#pragma unroll
    for (int i = 0; i < 4; i++)
#pragma unroll
        for (int rg = 0; rg < 4; rg++) {
            float p = 0.0f, q = 0.0f;
#pragma unroll
            for (int j = 0; j < 4; j++) {
                float v = acc[i][j][rg];
                p += v; q += v * v;
            }
#pragma unroll
            for (int off = 1; off < 16; off <<= 1) {
                p += __shfl_xor(p, off);
                q += __shfl_xor(q, off);
            }
            if (l16 == 0) {
                int rl = i * 16 + quad * 4 + rg;
                redS[wave][rl] = p;
                redS2[wave][rl] = q;
            }
        }
    __syncthreads();
#pragma unroll
    for (int i = 0; i < 4; i++)
#pragma unroll
        for (int rg = 0; rg < 4; rg++) {
            int rl = i * 16 + quad * 4 + rg;
            float s = redS[0][rl] + redS[1][rl] + redS[2][rl] + redS[3][rl];
            float qq = redS2[0][rl] + redS2[1][rl] + redS2[2][rl] + redS2[3][rl];
            float mean = s * (1.0f / 256.0f);
            float rstd = 1.0f / sqrtf(qq * (1.0f / 256.0f) - mean * mean + 1e-5f);
            size_t orow = (size_t)(m0 + rl) * 256;
#pragma unroll
            for (int j = 0; j < 4; j++) {
                int col = wn + j * 16 + l16;
                float y = (acc[i][j][rg] - mean) * rstd * g1j[j] + b1j[j];
                h[orow + col] = y;
                h_bf[orow + col] = f2bf(y);
            }
        }
}

__global__ __launch_bounds__(256) void cur_update_kernel(
    float* __restrict__ cur, const float* __restrict__ posupd, const float* __restrict__ ps, int l)
{
    const int i = blockIdx.x * 256 + threadIdx.x;
    cur[i] += ps[l] * posupd[i];
}

// ================= MFMA attention: one block per graph, wave w -> heads {w, w+4} =================
__global__ __launch_bounds__(256) void attn_mfma_kernel(
    const unsigned short* __restrict__ qkv, unsigned short* __restrict__ o)
{
    __shared__ __align__(16) unsigned short pS[4][64 * 72];
    __shared__ __align__(16) unsigned short vtS[4][32 * 72];
    const int g = blockIdx.x;
    const int tid = threadIdx.x;
    const int lane = tid & 63, wave = tid >> 6;
    const int quad = lane >> 4, l16 = lane & 15;
    const unsigned short* base = qkv + (size_t)g * 64 * 768;
    const float scale = 0.17677669529663687f;

    for (int hh = wave; hh < 8; hh += 4) {
        short8 aq[4], bk[4];
#pragma unroll
        for (int i = 0; i < 4; i++)
            aq[i] = *(const short8*)(base + (size_t)(i * 16 + l16) * 768 + hh * 32 + quad * 8);
#pragma unroll
        for (int j = 0; j < 4; j++)
            bk[j] = *(const short8*)(base + (size_t)(j * 16 + l16) * 768 + 256 + hh * 32 + quad * 8);
        {
            const unsigned short* vrow = base + (size_t)lane * 768 + 512 + hh * 32;
#pragma unroll
            for (int d = 0; d < 32; d++)
                vtS[wave][d * 72 + lane] = vrow[d];
        }
        f32x4 sc[4][4];
#pragma unroll
        for (int i = 0; i < 4; i++)
#pragma unroll
            for (int j = 0; j < 4; j++) sc[i][j] = (f32x4){0.f, 0.f, 0.f, 0.f};
#pragma unroll
        for (int i = 0; i < 4; i++)
#pragma unroll
            for (int j = 0; j < 4; j++)
                sc[i][j] = __builtin_amdgcn_mfma_f32_16x16x32_bf16(aq[i], bk[j], sc[i][j], 0, 0, 0);
#pragma unroll
        for (int i = 0; i < 4; i++)
#pragma unroll
            for (int rg = 0; rg < 4; rg++) {
                float v[4];
                float mx = -1e30f;
#pragma unroll
                for (int j = 0; j < 4; j++) {
                    v[j] = sc[i][j][rg] * scale;
                    mx = fmaxf(mx, v[j]);
                }
#pragma unroll
                for (int off = 1; off < 16; off <<= 1) mx = fmaxf(mx, __shfl_xor(mx, off));
                float sum = 0.0f;
#pragma unroll
                for (int j = 0; j < 4; j++) {
                    v[j] = exp_f(v[j] - mx);
                    sum += v[j];
                }
#pragma unroll
                for (int off = 1; off < 16; off <<= 1) sum += __shfl_xor(sum, off);
                float inv = __builtin_amdgcn_rcpf(sum);
                int row = i * 16 + quad * 4 + rg;
#pragma unroll
                for (int j = 0; j < 4; j++)
                    pS[wave][row * 72 + j * 16 + l16] = f2bf(v[j] * inv);
            }
        f32x4 oc[4][2];
#pragma unroll
        for (int i = 0; i < 4; i++)
#pragma unroll
            for (int j = 0; j < 2; j++) oc[i][j] = (f32x4){0.f, 0.f, 0.f, 0.f};
#pragma unroll
        for (int k0 = 0; k0 < 64; k0 += 32) {
            short8 ap[4], bv[2];
#pragma unroll
            for (int i = 0; i < 4; i++)
                ap[i] = *(const short8*)&pS[wave][(i * 16 + l16) * 72 + k0 + quad * 8];
#pragma unroll
            for (int j = 0; j < 2; j++)
                bv[j] = *(const short8*)&vtS[wave][(j * 16 + l16) * 72 + k0 + quad * 8];
#pragma unroll
            for (int i = 0; i < 4; i++)
#pragma unroll
                for (int j = 0; j < 2; j++)
                    oc[i][j] = __builtin_amdgcn_mfma_f32_16x16x32_bf16(ap[i], bv[j], oc[i][j], 0, 0, 0);
        }
#pragma unroll
        for (int i = 0; i < 4; i++)
#pragma unroll
            for (int rg = 0; rg < 4; rg++) {
                int row = i * 16 + quad * 4 + rg;
                unsigned short* ob = o + (size_t)(g * 64 + row) * 256 + hh * 32;
#pragma unroll
                for (int j = 0; j < 2; j++)
                    ob[j * 16 + l16] = f2bf(oc[i][j][rg]);
            }
    }
}

extern "C" void kernel_launch(void* const* d_in, const int* in_sizes, int n_in,
                              void* d_out, int out_size, void* d_ws, size_t ws_size,
                              hipStream_t stream)
{
    const float* x    = (const float*)d_in[0];
    const float* pos  = (const float*)d_in[1];
    const int*   ei   = (const int*)d_in[2];
    const float* pe_w1 = (const float*)d_in[5];
    const float* pe_b1 = (const float*)d_in[6];
    const float* pe_w2 = (const float*)d_in[7];
    const float* pe_b2 = (const float*)d_in[8];
    const float* pe_lg = (const float*)d_in[9];
    const float* pe_lb = (const float*)d_in[10];
    const float* ph_w1 = (const float*)d_in[11];
    const float* ph_b1 = (const float*)d_in[12];
    const float* ph_w2 = (const float*)d_in[13];
    const float* ph_b2 = (const float*)d_in[14];
    const float* ph_lg = (const float*)d_in[15];
    const float* ph_lb = (const float*)d_in[16];
    const float* px_w1 = (const float*)d_in[17];
    const float* px_b1 = (const float*)d_in[18];
    const float* px_w2 = (const float*)d_in[19];
    const float* px_b2 = (const float*)d_in[20];
    const float* ain_w = (const float*)d_in[21];
    const float* ain_b = (const float*)d_in[22];
    const float* aout_w = (const float*)d_in[23];
    const float* aout_b = (const float*)d_in[24];
    const float* lnh_g = (const float*)d_in[25];
    const float* lnh_b = (const float*)d_in[26];
    const float* lna_g = (const float*)d_in[27];
    const float* lna_b = (const float*)d_in[28];
    const float* ff_w1 = (const float*)d_in[29];
    const float* ff_b1 = (const float*)d_in[30];
    const float* ff_w2 = (const float*)d_in[31];
    const float* ff_b2 = (const float*)d_in[32];
    const float* ps    = (const float*)d_in[33];

    char* p = (char*)d_ws;
    auto alloc = [&](size_t bytes) { char* r = p; p += (bytes + 63) & ~(size_t)63; return r; };
    float* h      = (float*)alloc((size_t)NTOTC * HC * 4);
    unsigned short* h_bf  = (unsigned short*)alloc((size_t)NTOTC * HC * 2);
    unsigned short* xcat_bf = (unsigned short*)alloc((size_t)NTOTC * 512 * 2);
    float* cur    = (float*)alloc((size_t)NTOTC * 3 * 4);
    float* posupd = (float*)alloc((size_t)NTOTC * 3 * 4);
    float* hmsg   = (float*)alloc((size_t)NTOTC * HC * 4);
    unsigned short* qkv_bf = (unsigned short*)alloc((size_t)NTOTC * 3 * HC * 2);
    unsigned short* o_bf   = (unsigned short*)alloc((size_t)NTOTC * HC * 2);
    unsigned short* ff1_bf = (unsigned short*)alloc((size_t)NTOTC * 4 * HC * 2);
    int* cnt  = (int*)alloc(16384 * 4);
    int* ptrw = (int*)alloc(16384 * 4);
    int* rowP = (int*)alloc((size_t)NEDGEC * 4);
    int* colP = (int*)alloc((size_t)NEDGEC * 4);
    float* zbias = (float*)alloc(512 * 4);
    unsigned short* w_pe1s = (unsigned short*)alloc((size_t)LC * 512 * 256 * 2);
    float*          w_last = (float*)alloc((size_t)LC * 256 * 4);
    unsigned short* w_pe2  = (unsigned short*)alloc((size_t)LC * 256 * 256 * 2);
    unsigned short* w_ph1  = (unsigned short*)alloc((size_t)LC * 256 * 256 * 2);
    unsigned short* w_ph2  = (unsigned short*)alloc((size_t)LC * 256 * 256 * 2);
    unsigned short* w_px1  = (unsigned short*)alloc((size_t)LC * 256 * 256 * 2);
    unsigned short* w_ain  = (unsigned short*)alloc((size_t)LC * 768 * 256 * 2);
    unsigned short* w_aout = (unsigned short*)alloc((size_t)LC * 256 * 256 * 2);
    unsigned short* w_ff1  = (unsigned short*)alloc((size_t)LC * 1024 * 256 * 2);
    unsigned short* w_ff2  = (unsigned short*)alloc((size_t)LC * 256 * 1024 * 2);

    // ---- counting sort of edges by col ----
    hipMemsetAsync(cnt, 0, 16384 * 4, stream);
    hipMemsetAsync(zbias, 0, 512 * 4, stream);
    hist_kernel<<<NEDGEC / 256, 256, 0, stream>>>(ei + NEDGEC, cnt);
    scan16k_kernel<<<1, 256, 0, stream>>>(cnt, ptrw);
    permute_kernel<<<NEDGEC / 256, 256, 0, stream>>>(ei, ei + NEDGEC, ptrw, rowP, colP);

    // ---- convert weights to bf16 ----
    conv_pe1_kernel<<<(LC * 256 * 513 + 255) / 256, 256, 0, stream>>>(pe_w1, w_pe1s, w_last);
    conv_bf16_kernel<<<1536, 256, 0, stream>>>(pe_w2, w_pe2, LC * 256 * 256);
    conv_bf16_kernel<<<1536, 256, 0, stream>>>(ph_w1, w_ph1, LC * 256 * 256);
    conv_bf16_kernel<<<1536, 256, 0, stream>>>(ph_w2, w_ph2, LC * 256 * 256);
    conv_bf16_kernel<<<1536, 256, 0, stream>>>(px_w1, w_px1, LC * 256 * 256);
    conv_bf16_kernel<<<4608, 256, 0, stream>>>(ain_w, w_ain, LC * 768 * 256);
    conv_bf16_kernel<<<1536, 256, 0, stream>>>(aout_w, w_aout, LC * 256 * 256);
    conv_bf16_kernel<<<6144, 256, 0, stream>>>(ff_w1, w_ff1, LC * 1024 * 256);
    conv_bf16_kernel<<<6144, 256, 0, stream>>>(ff_w2, w_ff2, LC * 256 * 1024);

    hipMemcpyAsync(h, x, (size_t)NTOTC * HC * 4, hipMemcpyDeviceToDevice, stream);
    hipMemcpyAsync(cur, pos, (size_t)NTOTC * 3 * 4, hipMemcpyDeviceToDevice, stream);
    conv_bf16_kernel<<<4096, 256, 0, stream>>>(x, h_bf, NTOTC * HC);

    for (int l = 0; l < LC; l++) {
        hipMemsetAsync(hmsg, 0, (size_t)NTOTC * HC * 4, stream);
        hipMemsetAsync(posupd, 0, (size_t)NTOTC * 3 * 4, stream);

        // xcat = h @ [W1a;W1b]^T
        mgemm_kernel<0, false, false, true><<<dim3(NTOTC / 128, 4), 256, 0, stream>>>(
            h_bf, w_pe1s + (size_t)l * 512 * 256, zbias,
            nullptr, nullptr, xcat_bf, NTOTC, 512, HC);

        fused_edge_kernel<<<NEDGEC / 64, 256, 0, stream>>>(
            xcat_bf, cur, rowP, colP,
            w_last + (size_t)l * 256, pe_b1 + (size_t)l * HC,
            w_pe2 + (size_t)l * 256 * 256, pe_b2 + (size_t)l * HC,
            pe_lg + (size_t)l * HC, pe_lb + (size_t)l * HC,
            w_px1 + (size_t)l * 256 * 256, px_b1 + (size_t)l * HC,
            px_w2 + (size_t)l * HC, px_b2 + l,
            hmsg, posupd);

        // phi_h fully fused
        phi_h_fused_kernel<<<NTOTC / 64, 256, 0, stream>>>(
            h, hmsg,
            w_ph1 + (size_t)l * 256 * 256, ph_b1 + (size_t)l * HC,
            w_ph2 + (size_t)l * 256 * 256, ph_b2 + (size_t)l * HC,
            ph_lg + (size_t)l * HC, ph_lb + (size_t)l * HC,
            lnh_g + (size_t)l * HC, lnh_b + (size_t)l * HC, h, h_bf);
        cur_update_kernel<<<(NTOTC * 3) / 256, 256, 0, stream>>>(cur, posupd, ps, l);

        // attention
        mgemm_kernel<0, false, false, true><<<dim3(NTOTC / 128, 6), 256, 0, stream>>>(
            h_bf, w_ain + (size_t)l * 768 * 256, ain_b + (size_t)l * 3 * HC,
            nullptr, nullptr, qkv_bf, NTOTC, 3 * HC, HC);
        attn_mfma_kernel<<<NTOTC / 64, 256, 0, stream>>>(qkv_bf, o_bf);
        node_fused_kernel<false><<<NTOTC / 64, 256, 0, stream>>>(
            o_bf, w_aout + (size_t)l * 256 * 256, aout_b + (size_t)l * HC,
            lna_g + (size_t)l * HC, lna_b + (size_t)l * HC,
            nullptr, nullptr, h, h_bf);

        // feed-forward with residual
        mgemm_kernel<2, false, false, true><<<dim3(NTOTC / 128, 8), 256, 0, stream>>>(
            h_bf, w_ff1 + (size_t)l * 1024 * 256, ff_b1 + (size_t)l * 4 * HC,
            nullptr, nullptr, ff1_bf, NTOTC, 4 * HC, HC);
        mgemm_kernel<0, true, true, true><<<dim3(NTOTC / 128, 2), 256, 0, stream>>>(
            ff1_bf, w_ff2 + (size_t)l * 256 * 1024, ff_b2 + (size_t)l * HC,
            h, h, h_bf, NTOTC, HC, 4 * HC);
    }

    hipMemcpyAsync(d_out, h, (size_t)NTOTC * HC * 4, hipMemcpyDeviceToDevice, stream);
    hipMemcpyAsync((float*)d_out + (size_t)NTOTC * HC, cur, (size_t)NTOTC * 3 * 4,
                   hipMemcpyDeviceToDevice, stream);
}

// Round 12
// 2390.463 us; speedup vs baseline: 1.0928x; 1.0023x over previous
//
#include <hip/hip_runtime.h>
#include <cstddef>
#include <cstdint>

#define NTOTC 16384
#define HC 256
#define LC 6
#define NEDGEC 262144
#define NHEADSC 8

typedef __attribute__((ext_vector_type(8))) short short8;
typedef __attribute__((ext_vector_type(4))) float f32x4;

__device__ __forceinline__ unsigned short f2bf(float f) {
    unsigned int u = __float_as_uint(f);
    u += 0x7fff + ((u >> 16) & 1);   // round-to-nearest-even
    return (unsigned short)(u >> 16);
}
__device__ __forceinline__ float bf2f(unsigned short s) {
    return __uint_as_float(((unsigned int)s) << 16);
}
__device__ __forceinline__ void async_copy16(const void* g, void* l) {
    __builtin_amdgcn_global_load_lds(
        (const __attribute__((address_space(1))) unsigned int*)g,
        (__attribute__((address_space(3))) unsigned int*)l, 16, 0, 0);
}
// fast transcendentals; ~1e-6 rel err, negligible vs bf16
__device__ __forceinline__ float exp_f(float v) {
    return __builtin_amdgcn_exp2f(v * 1.4426950408889634f);
}
__device__ __forceinline__ float silu_f(float v) {
    return v * __builtin_amdgcn_rcpf(1.0f + __builtin_amdgcn_exp2f(-v * 1.4426950408889634f));
}
__device__ __forceinline__ float tanh_f(float v) {
    float e = __builtin_amdgcn_exp2f(v * 2.8853900817779268f);   // e^(2v)
    return 1.0f - 2.0f * __builtin_amdgcn_rcpf(1.0f + e);
}

// ================= weight conversion =================
__global__ __launch_bounds__(256) void conv_bf16_kernel(
    const float* __restrict__ in, unsigned short* __restrict__ out, int n)
{
    for (int i = blockIdx.x * 256 + threadIdx.x; i < n; i += gridDim.x * 256)
        out[i] = f2bf(in[i]);
}

// phi_e_w1 [L,256,513] -> stacked bf16 [L,512,256] ([W1a;W1b]) + fp32 dist column [L,256]
__global__ __launch_bounds__(256) void conv_pe1_kernel(
    const float* __restrict__ in, unsigned short* __restrict__ outk, float* __restrict__ wlast)
{
    int idx = blockIdx.x * 256 + threadIdx.x;
    if (idx >= LC * 256 * 513) return;
    int l = idx / (256 * 513);
    int rem = idx % (256 * 513);
    int n = rem / 513;
    int k = rem % 513;
    float v = in[idx];
    if (k == 512) wlast[l * 256 + n] = v;
    else if (k < 256) outk[(size_t)l * 512 * 256 + (size_t)n * 256 + k] = f2bf(v);
    else outk[(size_t)l * 512 * 256 + (size_t)(256 + n) * 256 + (k - 256)] = f2bf(v);
}

// ================= counting sort of edges by col =================
__global__ __launch_bounds__(256) void hist_kernel(
    const int* __restrict__ col, int* __restrict__ cnt)
{
    int e = blockIdx.x * 256 + threadIdx.x;
    atomicAdd(&cnt[col[e]], 1);
}

__global__ __launch_bounds__(256) void scan16k_kernel(
    const int* __restrict__ cnt, int* __restrict__ ptrw)
{
    __shared__ int partial[256];
    const int t = threadIdx.x;
    const int base = t * 64;
    int loc[64];
    int s = 0;
#pragma unroll
    for (int i = 0; i < 64; i++) { loc[i] = s; s += cnt[base + i]; }
    partial[t] = s;
    __syncthreads();
    if (t == 0) {
        int run = 0;
        for (int i = 0; i < 256; i++) { int tmp = partial[i]; partial[i] = run; run += tmp; }
    }
    __syncthreads();
    int off = partial[t];
#pragma unroll
    for (int i = 0; i < 64; i++) ptrw[base + i] = off + loc[i];
}

__global__ __launch_bounds__(256) void permute_kernel(
    const int* __restrict__ row, const int* __restrict__ col, int* __restrict__ ptrw,
    int* __restrict__ rowP, int* __restrict__ colP)
{
    int e = blockIdx.x * 256 + threadIdx.x;
    int c = col[e];
    int pos = atomicAdd(&ptrw[c], 1);
    rowP[pos] = row[e];
    colP[pos] = c;
}

// ================= generic MFMA GEMM: C = act(A @ W^T + bias)(+R) =================
template<int ACT, bool RES, bool WF, bool WB>
__global__ __launch_bounds__(256) void mgemm_kernel(
    const unsigned short* __restrict__ A, const unsigned short* __restrict__ W,
    const float* __restrict__ bias, const float* __restrict__ R,
    float* __restrict__ Cf, unsigned short* __restrict__ Cb,
    int M, int N, int K)
{
    __shared__ unsigned short As[128 * 32];
    __shared__ unsigned short Bs[128 * 32];
    const int tid = threadIdx.x;
    const int lane = tid & 63, wave = tid >> 6;
    const int quad = lane >> 4, l16 = lane & 15;
    const int wm = (wave >> 1) * 64, wn = (wave & 1) * 64;
    const int m0 = blockIdx.x * 128, n0 = blockIdx.y * 128;
    f32x4 acc[4][4] = {};
    const int rbase = (lane >> 2);
    const int kk = (lane & 3) * 8;

    for (int k0 = 0; k0 < K; k0 += 32) {
#pragma unroll
        for (int c = 0; c < 2; c++) {
            int t = wave * 2 + c;
            int r = t * 16 + rbase;
            async_copy16(A + (size_t)(m0 + r) * K + k0 + kk, &As[t * 512 + lane * 8]);
            async_copy16(W + (size_t)(n0 + r) * K + k0 + kk, &Bs[t * 512 + lane * 8]);
        }
        __syncthreads();
        short8 af[4], bfr[4];
#pragma unroll
        for (int i = 0; i < 4; i++)
            af[i] = *(const short8*)&As[(wm + i * 16 + l16) * 32 + quad * 8];
#pragma unroll
        for (int j = 0; j < 4; j++)
            bfr[j] = *(const short8*)&Bs[(wn + j * 16 + l16) * 32 + quad * 8];
#pragma unroll
        for (int i = 0; i < 4; i++)
#pragma unroll
            for (int j = 0; j < 4; j++)
                acc[i][j] = __builtin_amdgcn_mfma_f32_16x16x32_bf16(af[i], bfr[j], acc[i][j], 0, 0, 0);
        __syncthreads();
    }
#pragma unroll
    for (int j = 0; j < 4; j++) {
        int col = n0 + wn + j * 16 + l16;
        float bi = bias[col];
#pragma unroll
        for (int i = 0; i < 4; i++) {
#pragma unroll
            for (int rg = 0; rg < 4; rg++) {
                int row = m0 + wm + i * 16 + quad * 4 + rg;
                float v = acc[i][j][rg] + bi;
                if (ACT == 1) v = silu_f(v);
                if (ACT == 2) v = 0.5f * v * (1.0f + erff(v * 0.7071067811865476f));
                if (RES) v += R[(size_t)row * N + col];
                if (WF) Cf[(size_t)row * N + col] = v;
                if (WB) Cb[(size_t)row * N + col] = f2bf(v);
            }
        }
    }
}

// ================= FUSED edge pipeline (M=64, rel/dist inline) =================
__global__ __launch_bounds__(256, 4) void fused_edge_kernel(
    const unsigned short* __restrict__ xcat, const float* __restrict__ cur,
    const int* __restrict__ rowP, const int* __restrict__ colP,
    const float* __restrict__ wlast, const float* __restrict__ b1,
    const unsigned short* __restrict__ W2, const float* __restrict__ b2,
    const float* __restrict__ lg, const float* __restrict__ lb,
    const unsigned short* __restrict__ W3, const float* __restrict__ b3,
    const float* __restrict__ w2v, const float* __restrict__ b2s,
    float* __restrict__ hmsg, float* __restrict__ posupd)
{
    __shared__ __align__(16) unsigned short tS[64 * 264];
    __shared__ float redS[4][64];
    __shared__ float redS2[4][64];
    __shared__ int rowS[64], colS[64], flagS[64];
    __shared__ float distS[64];
    __shared__ float relS[64][3];
    __shared__ float cfS[64];

    const int tid = threadIdx.x;
    const int lane = tid & 63, wave = tid >> 6;
    const int quad = lane >> 4, l16 = lane & 15;
    const int wn = wave * 64;
    const int m0 = blockIdx.x * 64;

    if (tid < 64) {
        int r = rowP[m0 + tid];
        int c = colP[m0 + tid];
        rowS[tid] = r;
        colS[tid] = c;
        float rx = cur[(size_t)r * 3 + 0] - cur[(size_t)c * 3 + 0];
        float ry = cur[(size_t)r * 3 + 1] - cur[(size_t)c * 3 + 1];
        float rz = cur[(size_t)r * 3 + 2] - cur[(size_t)c * 3 + 2];
        relS[tid][0] = rx;
        relS[tid][1] = ry;
        relS[tid][2] = rz;
        float dx = rx + 1e-8f, dy = ry + 1e-8f, dz = rz + 1e-8f;  // ref adds eps per component
        distS[tid] = sqrtf(dx * dx + dy * dy + dz * dz);
    }
    __syncthreads();
    if (tid < 64) flagS[tid] = (tid == 63) || (colS[tid] != colS[tid + 1]);

    // ---- Stage 1: gather-add replacing edge GEMM1 ----
    {
        const int cb = lane * 4;
        float4 wl4 = *(const float4*)&wlast[cb];
        float4 b14 = *(const float4*)&b1[cb];
#pragma unroll
        for (int rr = 0; rr < 16; rr++) {
            int r = rr * 4 + wave;
            const ushort4 ua = *(const ushort4*)(xcat + (size_t)rowS[r] * 512 + cb);
            const ushort4 ub = *(const ushort4*)(xcat + (size_t)colS[r] * 512 + 256 + cb);
            float dv = distS[r];
            float v0 = bf2f(ua.x) + bf2f(ub.x) + dv * wl4.x + b14.x;
            float v1 = bf2f(ua.y) + bf2f(ub.y) + dv * wl4.y + b14.y;
            float v2 = bf2f(ua.z) + bf2f(ub.z) + dv * wl4.z + b14.z;
            float v3 = bf2f(ua.w) + bf2f(ub.w) + dv * wl4.w + b14.w;
            ushort4 o;
            o.x = f2bf(silu_f(v0));
            o.y = f2bf(silu_f(v1));
            o.z = f2bf(silu_f(v2));
            o.w = f2bf(silu_f(v3));
            *(ushort4*)&tS[r * 264 + cb] = o;
        }
    }
    __syncthreads();

    f32x4 acc[4][4];

    // ---- GEMM2: K=256, A from tS, W2 direct; NO barriers in k-loop ----
#pragma unroll
    for (int i = 0; i < 4; i++)
#pragma unroll
        for (int j = 0; j < 4; j++) acc[i][j] = (f32x4){0.f, 0.f, 0.f, 0.f};
#pragma unroll
    for (int k0 = 0; k0 < 256; k0 += 32) {
        short8 af[4], bfr[4];
#pragma unroll
        for (int j = 0; j < 4; j++)
            bfr[j] = *(const short8*)(W2 + (size_t)(wn + j * 16 + l16) * 256 + k0 + quad * 8);
#pragma unroll
        for (int i = 0; i < 4; i++)
            af[i] = *(const short8*)&tS[(i * 16 + l16) * 264 + k0 + quad * 8];
#pragma unroll
        for (int i = 0; i < 4; i++)
#pragma unroll
            for (int j = 0; j < 4; j++)
                acc[i][j] = __builtin_amdgcn_mfma_f32_16x16x32_bf16(af[i], bfr[j], acc[i][j], 0, 0, 0);
    }
    __syncthreads();
    // epilogue 2: LN -> m -> tS (overwrite)
    {
        float b2j[4], gj[4], bbj[4];
#pragma unroll
        for (int j = 0; j < 4; j++) {
            int col = wn + j * 16 + l16;
            b2j[j] = b2[col];
            gj[j] = lg[col];
            bbj[j] = lb[col];
        }
#pragma unroll
        for (int i = 0; i < 4; i++)
#pragma unroll
            for (int rg = 0; rg < 4; rg++) {
                float p = 0.0f, q = 0.0f;
#pragma unroll
                for (int j = 0; j < 4; j++) {
                    float v = acc[i][j][rg] + b2j[j];
                    p += v; q += v * v;
                }
#pragma unroll
                for (int off = 1; off < 16; off <<= 1) {
                    p += __shfl_xor(p, off);
                    q += __shfl_xor(q, off);
                }
                if (l16 == 0) {
                    int row = i * 16 + quad * 4 + rg;
                    redS[wave][row] = p;
                    redS2[wave][row] = q;
                }
            }
        __syncthreads();
#pragma unroll
        for (int i = 0; i < 4; i++)
#pragma unroll
            for (int rg = 0; rg < 4; rg++) {
                int row = i * 16 + quad * 4 + rg;
                float s = redS[0][row] + redS[1][row] + redS[2][row] + redS[3][row];
                float qq = redS2[0][row] + redS2[1][row] + redS2[2][row] + redS2[3][row];
                float mean = s * (1.0f / 256.0f);
                float rstd = 1.0f / sqrtf(qq * (1.0f / 256.0f) - mean * mean + 1e-5f);
#pragma unroll
                for (int j = 0; j < 4; j++) {
                    int col = wn + j * 16 + l16;
                    float v = acc[i][j][rg] + b2j[j];
                    tS[row * 264 + col] = f2bf((v - mean) * rstd * gj[j] + bbj[j]);
                }
            }
    }
    __syncthreads();

    // ---- segmented scatter of m into hmsg ----
    {
        const int c = tid;
        float s = 0.0f;
#pragma unroll
        for (int r = 0; r < 64; r++) {
            s += bf2f(tS[r * 264 + c]);
            if (flagS[r]) {
                atomicAdd(&hmsg[(size_t)colS[r] * 256 + c], s);
                s = 0.0f;
            }
        }
    }

    // ---- GEMM3: K=256, A = m from tS, W3 direct ----
#pragma unroll
    for (int i = 0; i < 4; i++)
#pragma unroll
        for (int j = 0; j < 4; j++) acc[i][j] = (f32x4){0.f, 0.f, 0.f, 0.f};
#pragma unroll
    for (int k0 = 0; k0 < 256; k0 += 32) {
        short8 af[4], bfr[4];
#pragma unroll
        for (int j = 0; j < 4; j++)
            bfr[j] = *(const short8*)(W3 + (size_t)(wn + j * 16 + l16) * 256 + k0 + quad * 8);
#pragma unroll
        for (int i = 0; i < 4; i++)
            af[i] = *(const short8*)&tS[(i * 16 + l16) * 264 + k0 + quad * 8];
#pragma unroll
        for (int i = 0; i < 4; i++)
#pragma unroll
            for (int j = 0; j < 4; j++)
                acc[i][j] = __builtin_amdgcn_mfma_f32_16x16x32_bf16(af[i], bfr[j], acc[i][j], 0, 0, 0);
    }
    // epilogue 3
    {
        float b3j[4], w2j[4];
#pragma unroll
        for (int j = 0; j < 4; j++) {
            int col = wn + j * 16 + l16;
            b3j[j] = b3[col];
            w2j[j] = w2v[col];
        }
#pragma unroll
        for (int i = 0; i < 4; i++)
#pragma unroll
            for (int rg = 0; rg < 4; rg++) {
                float p = 0.0f;
#pragma unroll
                for (int j = 0; j < 4; j++)
                    p += silu_f(acc[i][j][rg] + b3j[j]) * w2j[j];
#pragma unroll
                for (int off = 1; off < 16; off <<= 1) p += __shfl_xor(p, off);
                if (l16 == 0) redS[wave][i * 16 + quad * 4 + rg] = p;
            }
        __syncthreads();
        if (tid < 64) {
            float tot = redS[0][tid] + redS[1][tid] + redS[2][tid] + redS[3][tid] + b2s[0];
            cfS[tid] = tanh_f(tot);
        }
        __syncthreads();
        if (tid < 3) {
            const int comp = tid;
            float s = 0.0f;
#pragma unroll
            for (int r = 0; r < 64; r++) {
                s += relS[r][comp] * cfS[r];
                if (flagS[r]) {
                    atomicAdd(&posupd[(size_t)colS[r] * 3 + comp], s);
                    s = 0.0f;
                }
            }
        }
    }
}

// ============ phi_h fused + cur-update + hmsg re-zero ============
// h = LN2(h + LN1(silu((h+hmsg)@W1^T+b1)@W2^T+b2)); cur += ps[l]*posupd (posupd zeroed);
// block zeroes its own hmsg rows for the next layer.
__global__ __launch_bounds__(256) void phi_h_fused_kernel(
    const float* __restrict__ h_in, float* __restrict__ hmsg,
    const unsigned short* __restrict__ W1, const float* __restrict__ b1v,
    const unsigned short* __restrict__ W2, const float* __restrict__ bias,
    const float* __restrict__ g1, const float* __restrict__ bb1,
    const float* __restrict__ g2, const float* __restrict__ bb2,
    float* __restrict__ h, unsigned short* __restrict__ h_bf,
    float* __restrict__ cur, float* __restrict__ posupd, const float* __restrict__ psv, int l)
{
    __shared__ __align__(16) unsigned short As[64 * 32];
    __shared__ __align__(16) unsigned short Bs[256 * 32];
    __shared__ __align__(16) unsigned short tS[64 * 264];
    __shared__ float redS[4][64];
    __shared__ float redS2[4][64];
    const int tid = threadIdx.x;
    const int lane = tid & 63, wave = tid >> 6;
    const int quad = lane >> 4, l16 = lane & 15;
    const int wn = wave * 64;
    const int m0 = blockIdx.x * 64;
    f32x4 acc[4][4] = {};
    const int rbase = (lane >> 2);
    const int kk = (lane & 3) * 8;

    // side job: cur += ps[l] * posupd; posupd = 0  (49152 elements over first 192 blocks)
    {
        int e = blockIdx.x * 256 + tid;
        if (e < NTOTC * 3) {
            cur[e] += psv[l] * posupd[e];
            posupd[e] = 0.0f;
        }
    }

    for (int k0 = 0; k0 < 256; k0 += 32) {
#pragma unroll
        for (int c = 0; c < 2; c++) {
            int u = c * 256 + tid;
            int r = u >> 3, kg = (u & 7) * 4;
            float4 a = *(const float4*)&h_in[(size_t)(m0 + r) * 256 + k0 + kg];
            float4 b = *(const float4*)&hmsg[(size_t)(m0 + r) * 256 + k0 + kg];
            ushort4 o4;
            o4.x = f2bf(a.x + b.x);
            o4.y = f2bf(a.y + b.y);
            o4.z = f2bf(a.z + b.z);
            o4.w = f2bf(a.w + b.w);
            *(ushort4*)&As[r * 32 + kg] = o4;
        }
#pragma unroll
        for (int c = 0; c < 4; c++) {
            int t = wave * 4 + c;
            int r = t * 16 + rbase;
            async_copy16(W1 + (size_t)r * 256 + k0 + kk, &Bs[t * 512 + lane * 8]);
        }
        __syncthreads();
        short8 bfr[4];
#pragma unroll
        for (int j = 0; j < 4; j++)
            bfr[j] = *(const short8*)&Bs[(wn + j * 16 + l16) * 32 + quad * 8];
#pragma unroll
        for (int i = 0; i < 4; i++) {
            short8 af = *(const short8*)&As[(i * 16 + l16) * 32 + quad * 8];
#pragma unroll
            for (int j = 0; j < 4; j++)
                acc[i][j] = __builtin_amdgcn_mfma_f32_16x16x32_bf16(af, bfr[j], acc[i][j], 0, 0, 0);
        }
        __syncthreads();
    }
    // zero this block's hmsg rows (fully consumed above) for the next layer
    {
        size_t base = (size_t)m0 * 256;
        float4 z = {0.f, 0.f, 0.f, 0.f};
#pragma unroll
        for (int t = 0; t < 16; t++)
            *(float4*)&hmsg[base + (size_t)(t * 256 + tid) * 4] = z;
    }
    {
        float b1j[4];
#pragma unroll
        for (int j = 0; j < 4; j++) b1j[j] = b1v[wn + j * 16 + l16];
#pragma unroll
        for (int i = 0; i < 4; i++)
#pragma unroll
            for (int rg = 0; rg < 4; rg++) {
                int row = i * 16 + quad * 4 + rg;
#pragma unroll
                for (int j = 0; j < 4; j++) {
                    int col = wn + j * 16 + l16;
                    tS[row * 264 + col] = f2bf(silu_f(acc[i][j][rg] + b1j[j]));
                }
            }
    }
    __syncthreads();

#pragma unroll
    for (int i = 0; i < 4; i++)
#pragma unroll
        for (int j = 0; j < 4; j++) acc[i][j] = (f32x4){0.f, 0.f, 0.f, 0.f};
#pragma unroll
    for (int k0 = 0; k0 < 256; k0 += 32) {
        short8 af[4], bfr[4];
#pragma unroll
        for (int j = 0; j < 4; j++)
            bfr[j] = *(const short8*)(W2 + (size_t)(wn + j * 16 + l16) * 256 + k0 + quad * 8);
#pragma unroll
        for (int i = 0; i < 4; i++)
            af[i] = *(const short8*)&tS[(i * 16 + l16) * 264 + k0 + quad * 8];
#pragma unroll
        for (int i = 0; i < 4; i++)
#pragma unroll
            for (int j = 0; j < 4; j++)
                acc[i][j] = __builtin_amdgcn_mfma_f32_16x16x32_bf16(af[i], bfr[j], acc[i][j], 0, 0, 0);
    }

    float bj[4], g1j[4], b1j[4], g2j[4], b2j[4];
#pragma unroll
    for (int j = 0; j < 4; j++) {
        int col = wn + j * 16 + l16;
        bj[j] = bias[col];
        g1j[j] = g1[col]; b1j[j] = bb1[col];
        g2j[j] = g2[col]; b2j[j] = bb2[col];
    }
#pragma unroll
    for (int i = 0; i < 4; i++)
#pragma unroll
        for (int rg = 0; rg < 4; rg++) {
            float p = 0.0f, q = 0.0f;
#pragma unroll
            for (int j = 0; j < 4; j++) {
                float v = acc[i][j][rg] + bj[j];
                p += v; q += v * v;
            }
#pragma unroll
            for (int off = 1; off < 16; off <<= 1) {
                p += __shfl_xor(p, off);
                q += __shfl_xor(q, off);
            }
            if (l16 == 0) {
                int rl = i * 16 + quad * 4 + rg;
                redS[wave][rl] = p;
                redS2[wave][rl] = q;
            }
        }
    __syncthreads();
#pragma unroll
    for (int i = 0; i < 4; i++)
#pragma unroll
        for (int rg = 0; rg < 4; rg++) {
            int rl = i * 16 + quad * 4 + rg;
            float s = redS[0][rl] + redS[1][rl] + redS[2][rl] + redS[3][rl];
            float qq = redS2[0][rl] + redS2[1][rl] + redS2[2][rl] + redS2[3][rl];
            float mean = s * (1.0f / 256.0f);
            float rstd = 1.0f / sqrtf(qq * (1.0f / 256.0f) - mean * mean + 1e-5f);
#pragma unroll
            for (int j = 0; j < 4; j++) {
                int col = wn + j * 16 + l16;
                float v = acc[i][j][rg] + bj[j];
                float hu = (v - mean) * rstd * g1j[j] + b1j[j];
                acc[i][j][rg] = hu + h_in[(size_t)(m0 + rl) * 256 + col];
            }
        }
    __syncthreads();
#pragma unroll
    for (int i = 0; i < 4; i++)
#pragma unroll
        for (int rg = 0; rg < 4; rg++) {
            float p = 0.0f, q = 0.0f;
#pragma unroll
            for (int j = 0; j < 4; j++) {
                float v = acc[i][j][rg];
                p += v; q += v * v;
            }
#pragma unroll
            for (int off = 1; off < 16; off <<= 1) {
                p += __shfl_xor(p, off);
                q += __shfl_xor(q, off);
            }
            if (l16 == 0) {
                int rl = i * 16 + quad * 4 + rg;
                redS[wave][rl] = p;
                redS2[wave][rl] = q;
            }
        }
    __syncthreads();
#pragma unroll
    for (int i = 0; i < 4; i++)
#pragma unroll
        for (int rg = 0; rg < 4; rg++) {
            int rl = i * 16 + quad * 4 + rg;
            float s = redS[0][rl] + redS[1][rl] + redS[2][rl] + redS[3][rl];
            float qq = redS2[0][rl] + redS2[1][rl] + redS2[2][rl] + redS2[3][rl];
            float mean = s * (1.0f / 256.0f);
            float rstd = 1.0f / sqrtf(qq * (1.0f / 256.0f) - mean * mean + 1e-5f);
            size_t orow = (size_t)(m0 + rl) * 256;
#pragma unroll
            for (int j = 0; j < 4; j++) {
                int col = wn + j * 16 + l16;
                float y = (acc[i][j][rg] - mean) * rstd * g2j[j] + b2j[j];
                h[orow + col] = y;
                h_bf[orow + col] = f2bf(y);
            }
        }
}

// ============ fused node GEMM + LN epilogue (attn-out path) ============
__global__ __launch_bounds__(256) void node_fused_kernel(
    const unsigned short* __restrict__ A, const unsigned short* __restrict__ W,
    const float* __restrict__ bias,
    const float* __restrict__ g1, const float* __restrict__ b1,
    float* __restrict__ h, unsigned short* __restrict__ h_bf)
{
    __shared__ unsigned short As[64 * 32];
    __shared__ unsigned short Bs[256 * 32];
    __shared__ float redS[4][64];
    __shared__ float redS2[4][64];
    const int tid = threadIdx.x;
    const int lane = tid & 63, wave = tid >> 6;
    const int quad = lane >> 4, l16 = lane & 15;
    const int wn = wave * 64;
    const int m0 = blockIdx.x * 64;
    f32x4 acc[4][4] = {};
    const int rbase = (lane >> 2);
    const int kk = (lane & 3) * 8;

    for (int k0 = 0; k0 < 256; k0 += 32) {
        {
            int r = wave * 16 + rbase;
            async_copy16(A + (size_t)(m0 + r) * 256 + k0 + kk, &As[wave * 512 + lane * 8]);
        }
#pragma unroll
        for (int c = 0; c < 4; c++) {
            int t = wave * 4 + c;
            int r = t * 16 + rbase;
            async_copy16(W + (size_t)r * 256 + k0 + kk, &Bs[t * 512 + lane * 8]);
        }
        __syncthreads();
        short8 bfr[4];
#pragma unroll
        for (int j = 0; j < 4; j++)
            bfr[j] = *(const short8*)&Bs[(wn + j * 16 + l16) * 32 + quad * 8];
#pragma unroll
        for (int i = 0; i < 4; i++) {
            short8 af = *(const short8*)&As[(i * 16 + l16) * 32 + quad * 8];
#pragma unroll
            for (int j = 0; j < 4; j++)
                acc[i][j] = __builtin_amdgcn_mfma_f32_16x16x32_bf16(af, bfr[j], acc[i][j], 0, 0, 0);
        }
        __syncthreads();
    }

    float bj[4], g1j[4], b1j[4];
#pragma unroll
    for (int j = 0; j < 4; j++) {
        int col = wn + j * 16 + l16;
        bj[j] = bias[col];
        g1j[j] = g1[col]; b1j[j] = b1[col];
    }

#pragma unroll
    for (int i = 0; i < 4; i++)
#pragma unroll
        for (int rg = 0; rg < 4; rg++) {
            int rl = i * 16 + quad * 4 + rg;
#pragma unroll
            for (int j = 0; j < 4; j++) {
                int col = wn + j * 16 + l16;
                acc[i][j][rg] += bj[j] + h[(size_t)(m0 + rl) * 256 + col];
            }
        }
#pragma unroll
    for (int i = 0; i < 4; i++)
#pragma unroll
        for (int rg = 0; rg < 4; rg++) {
            float p = 0.0f, q = 0.0f;
#pragma unroll
            for (int j = 0; j < 4; j++) {
                float v = acc[i][j][rg];
                p += v; q += v * v;
            }
#pragma unroll
            for (int off = 1; off < 16; off <<= 1) {
                p += __shfl_xor(p, off);
                q += __shfl_xor(q, off);
            }
            if (l16 == 0) {
                int rl = i * 16 + quad * 4 + rg;
                redS[wave][rl] = p;
                redS2[wave][rl] = q;
            }
        }
    __syncthreads();
#pragma unroll
    for (int i = 0; i < 4; i++)
#pragma unroll
        for (int rg = 0; rg < 4; rg++) {
            int rl = i * 16 + quad * 4 + rg;
            float s = redS[0][rl] + redS[1][rl] + redS[2][rl] + redS[3][rl];
            float qq = redS2[0][rl] + redS2[1][rl] + redS2[2][rl] + redS2[3][rl];
            float mean = s * (1.0f / 256.0f);
            float rstd = 1.0f / sqrtf(qq * (1.0f / 256.0f) - mean * mean + 1e-5f);
            size_t orow = (size_t)(m0 + rl) * 256;
#pragma unroll
            for (int j = 0; j < 4; j++) {
                int col = wn + j * 16 + l16;
                float y = (acc[i][j][rg] - mean) * rstd * g1j[j] + b1j[j];
                h[orow + col] = y;
                h_bf[orow + col] = f2bf(y);
            }
        }
}

// ================= fused QKV projection + MFMA attention =================
// One block per graph. Wave w handles heads {w, w+4} in 2 passes.
// Pass: GEMM (A = h rows staged, B = w_ain direct) for this head's 96 cols ->
// q/k/v^T in wave-private LDS -> softmax(QK^T)V -> o.
__global__ __launch_bounds__(256) void qkv_attn_kernel(
    const unsigned short* __restrict__ hB, const unsigned short* __restrict__ W,
    const float* __restrict__ bias, unsigned short* __restrict__ o)
{
    __shared__ __align__(16) unsigned short As[64 * 32];       // 4 KB
    __shared__ __align__(16) unsigned short scr[4][5120];      // 40 KB: q(64x40)+k(64x40) / P(64x72)
    __shared__ __align__(16) unsigned short vtS[4][32 * 72];   // 18.4 KB
    const int g = blockIdx.x;
    const int tid = threadIdx.x;
    const int lane = tid & 63, wave = tid >> 6;
    const int quad = lane >> 4, l16 = lane & 15;
    const int m0 = g * 64;
    const int rbase = lane >> 2;
    const int kk = (lane & 3) * 8;
    const float scale = 0.17677669529663687f;   // 1/sqrt(32)

#pragma unroll
    for (int s = 0; s < 2; s++) {
        const int hh = wave + s * 4;
        f32x4 acc[4][6];
#pragma unroll
        for (int i = 0; i < 4; i++)
#pragma unroll
            for (int jt = 0; jt < 6; jt++) acc[i][jt] = (f32x4){0.f, 0.f, 0.f, 0.f};

        for (int k0 = 0; k0 < 256; k0 += 32) {
            {
                int r = wave * 16 + rbase;
                async_copy16(hB + (size_t)(m0 + r) * 256 + k0 + kk, &As[wave * 512 + lane * 8]);
            }
            __syncthreads();
            short8 af[4], bfr[6];
#pragma unroll
            for (int jt = 0; jt < 6; jt++) {
                int n = (jt >> 1) * 256 + hh * 32 + (jt & 1) * 16 + l16;
                bfr[jt] = *(const short8*)(W + (size_t)n * 256 + k0 + quad * 8);
            }
#pragma unroll
            for (int i = 0; i < 4; i++)
                af[i] = *(const short8*)&As[(i * 16 + l16) * 32 + quad * 8];
#pragma unroll
            for (int i = 0; i < 4; i++)
#pragma unroll
                for (int jt = 0; jt < 6; jt++)
                    acc[i][jt] = __builtin_amdgcn_mfma_f32_16x16x32_bf16(af[i], bfr[jt], acc[i][jt], 0, 0, 0);
            __syncthreads();
        }

        // epilogue: q,k -> scr (stride 40), v -> vtS transposed (stride 72)
        unsigned short* qb = &scr[wave][0];
        unsigned short* kb = &scr[wave][2560];
#pragma unroll
        for (int jt = 0; jt < 6; jt++) {
            int seg = jt >> 1;
            int dcol = (jt & 1) * 16 + l16;
            float bi = bias[seg * 256 + hh * 32 + dcol];
#pragma unroll
            for (int i = 0; i < 4; i++)
#pragma unroll
                for (int rg = 0; rg < 4; rg++) {
                    int row = i * 16 + quad * 4 + rg;
                    unsigned short val = f2bf(acc[i][jt][rg] + bi);
                    if (seg == 0) qb[row * 40 + dcol] = val;
                    else if (seg == 1) kb[row * 40 + dcol] = val;
                    else vtS[wave][dcol * 72 + row] = val;
                }
        }
        // load Q/K frags before P overwrites scr
        short8 aq[4], bk[4];
#pragma unroll
        for (int i = 0; i < 4; i++)
            aq[i] = *(const short8*)&qb[(i * 16 + l16) * 40 + quad * 8];
#pragma unroll
        for (int j = 0; j < 4; j++)
            bk[j] = *(const short8*)&kb[(j * 16 + l16) * 40 + quad * 8];
        __asm__ __volatile__("s_waitcnt lgkmcnt(0)" ::: "memory");

        // S = Q @ K^T
        f32x4 sc[4][4];
#pragma unroll
        for (int i = 0; i < 4; i++)
#pragma unroll
            for (int j = 0; j < 4; j++) sc[i][j] = (f32x4){0.f, 0.f, 0.f, 0.f};
#pragma unroll
        for (int i = 0; i < 4; i++)
#pragma unroll
            for (int j = 0; j < 4; j++)
                sc[i][j] = __builtin_amdgcn_mfma_f32_16x16x32_bf16(aq[i], bk[j], sc[i][j], 0, 0, 0);
        // softmax -> P in scr (stride 72)
        unsigned short* pb = &scr[wave][0];
#pragma unroll
        for (int i = 0; i < 4; i++)
#pragma unroll
            for (int rg = 0; rg < 4; rg++) {
                float v[4];
                float mx = -1e30f;
#pragma unroll
                for (int j = 0; j < 4; j++) {
                    v[j] = sc[i][j][rg] * scale;
                    mx = fmaxf(mx, v[j]);
                }
#pragma unroll
                for (int off = 1; off < 16; off <<= 1) mx = fmaxf(mx, __shfl_xor(mx, off));
                float sum = 0.0f;
#pragma unroll
                for (int j = 0; j < 4; j++) {
                    v[j] = exp_f(v[j] - mx);
                    sum += v[j];
                }
#pragma unroll
                for (int off = 1; off < 16; off <<= 1) sum += __shfl_xor(sum, off);
                float inv = __builtin_amdgcn_rcpf(sum);
                int row = i * 16 + quad * 4 + rg;
#pragma unroll
                for (int j = 0; j < 4; j++)
                    pb[row * 72 + j * 16 + l16] = f2bf(v[j] * inv);
            }
        // O = P @ V
        f32x4 oc[4][2];
#pragma unroll
        for (int i = 0; i < 4; i++)
#pragma unroll
            for (int j = 0; j < 2; j++) oc[i][j] = (f32x4){0.f, 0.f, 0.f, 0.f};
#pragma unroll
        for (int k0 = 0; k0 < 64; k0 += 32) {
            short8 ap[4], bv[2];
#pragma unroll
            for (int i = 0; i < 4; i++)
                ap[i] = *(const short8*)&pb[(i * 16 + l16) * 72 + k0 + quad * 8];
#pragma unroll
            for (int j = 0; j < 2; j++)
                bv[j] = *(const short8*)&vtS[wave][(j * 16 + l16) * 72 + k0 + quad * 8];
#pragma unroll
            for (int i = 0; i < 4; i++)
#pragma unroll
                for (int j = 0; j < 2; j++)
                    oc[i][j] = __builtin_amdgcn_mfma_f32_16x16x32_bf16(ap[i], bv[j], oc[i][j], 0, 0, 0);
        }
#pragma unroll
        for (int i = 0; i < 4; i++)
#pragma unroll
            for (int rg = 0; rg < 4; rg++) {
                int row = i * 16 + quad * 4 + rg;
                unsigned short* ob = o + (size_t)(m0 + row) * 256 + hh * 32;
#pragma unroll
                for (int j = 0; j < 2; j++)
                    ob[j * 16 + l16] = f2bf(oc[i][j][rg]);
            }
    }
}

extern "C" void kernel_launch(void* const* d_in, const int* in_sizes, int n_in,
                              void* d_out, int out_size, void* d_ws, size_t ws_size,
                              hipStream_t stream)
{
    const float* x    = (const float*)d_in[0];
    const float* pos  = (const float*)d_in[1];
    const int*   ei   = (const int*)d_in[2];
    const float* pe_w1 = (const float*)d_in[5];
    const float* pe_b1 = (const float*)d_in[6];
    const float* pe_w2 = (const float*)d_in[7];
    const float* pe_b2 = (const float*)d_in[8];
    const float* pe_lg = (const float*)d_in[9];
    const float* pe_lb = (const float*)d_in[10];
    const float* ph_w1 = (const float*)d_in[11];
    const float* ph_b1 = (const float*)d_in[12];
    const float* ph_w2 = (const float*)d_in[13];
    const float* ph_b2 = (const float*)d_in[14];
    const float* ph_lg = (const float*)d_in[15];
    const float* ph_lb = (const float*)d_in[16];
    const float* px_w1 = (const float*)d_in[17];
    const float* px_b1 = (const float*)d_in[18];
    const float* px_w2 = (const float*)d_in[19];
    const float* px_b2 = (const float*)d_in[20];
    const float* ain_w = (const float*)d_in[21];
    const float* ain_b = (const float*)d_in[22];
    const float* aout_w = (const float*)d_in[23];
    const float* aout_b = (const float*)d_in[24];
    const float* lnh_g = (const float*)d_in[25];
    const float* lnh_b = (const float*)d_in[26];
    const float* lna_g = (const float*)d_in[27];
    const float* lna_b = (const float*)d_in[28];
    const float* ff_w1 = (const float*)d_in[29];
    const float* ff_b1 = (const float*)d_in[30];
    const float* ff_w2 = (const float*)d_in[31];
    const float* ff_b2 = (const float*)d_in[32];
    const float* ps    = (const float*)d_in[33];

    char* p = (char*)d_ws;
    auto alloc = [&](size_t bytes) { char* r = p; p += (bytes + 63) & ~(size_t)63; return r; };
    float* h      = (float*)alloc((size_t)NTOTC * HC * 4);
    unsigned short* h_bf  = (unsigned short*)alloc((size_t)NTOTC * HC * 2);
    unsigned short* xcat_bf = (unsigned short*)alloc((size_t)NTOTC * 512 * 2);
    float* cur    = (float*)alloc((size_t)NTOTC * 3 * 4);
    float* posupd = (float*)alloc((size_t)NTOTC * 3 * 4);
    float* hmsg   = (float*)alloc((size_t)NTOTC * HC * 4);
    unsigned short* o_bf   = (unsigned short*)alloc((size_t)NTOTC * HC * 2);
    unsigned short* ff1_bf = (unsigned short*)alloc((size_t)NTOTC * 4 * HC * 2);
    int* cnt  = (int*)alloc(16384 * 4);
    int* ptrw = (int*)alloc(16384 * 4);
    int* rowP = (int*)alloc((size_t)NEDGEC * 4);
    int* colP = (int*)alloc((size_t)NEDGEC * 4);
    float* zbias = (float*)alloc(512 * 4);
    unsigned short* w_pe1s = (unsigned short*)alloc((size_t)LC * 512 * 256 * 2);
    float*          w_last = (float*)alloc((size_t)LC * 256 * 4);
    unsigned short* w_pe2  = (unsigned short*)alloc((size_t)LC * 256 * 256 * 2);
    unsigned short* w_ph1  = (unsigned short*)alloc((size_t)LC * 256 * 256 * 2);
    unsigned short* w_ph2  = (unsigned short*)alloc((size_t)LC * 256 * 256 * 2);
    unsigned short* w_px1  = (unsigned short*)alloc((size_t)LC * 256 * 256 * 2);
    unsigned short* w_ain  = (unsigned short*)alloc((size_t)LC * 768 * 256 * 2);
    unsigned short* w_aout = (unsigned short*)alloc((size_t)LC * 256 * 256 * 2);
    unsigned short* w_ff1  = (unsigned short*)alloc((size_t)LC * 1024 * 256 * 2);
    unsigned short* w_ff2  = (unsigned short*)alloc((size_t)LC * 256 * 1024 * 2);

    // ---- counting sort of edges by col ----
    hipMemsetAsync(cnt, 0, 16384 * 4, stream);
    hipMemsetAsync(zbias, 0, 512 * 4, stream);
    hist_kernel<<<NEDGEC / 256, 256, 0, stream>>>(ei + NEDGEC, cnt);
    scan16k_kernel<<<1, 256, 0, stream>>>(cnt, ptrw);
    permute_kernel<<<NEDGEC / 256, 256, 0, stream>>>(ei, ei + NEDGEC, ptrw, rowP, colP);

    // ---- convert weights to bf16 ----
    conv_pe1_kernel<<<(LC * 256 * 513 + 255) / 256, 256, 0, stream>>>(pe_w1, w_pe1s, w_last);
    conv_bf16_kernel<<<1536, 256, 0, stream>>>(pe_w2, w_pe2, LC * 256 * 256);
    conv_bf16_kernel<<<1536, 256, 0, stream>>>(ph_w1, w_ph1, LC * 256 * 256);
    conv_bf16_kernel<<<1536, 256, 0, stream>>>(ph_w2, w_ph2, LC * 256 * 256);
    conv_bf16_kernel<<<1536, 256, 0, stream>>>(px_w1, w_px1, LC * 256 * 256);
    conv_bf16_kernel<<<4608, 256, 0, stream>>>(ain_w, w_ain, LC * 768 * 256);
    conv_bf16_kernel<<<1536, 256, 0, stream>>>(aout_w, w_aout, LC * 256 * 256);
    conv_bf16_kernel<<<6144, 256, 0, stream>>>(ff_w1, w_ff1, LC * 1024 * 256);
    conv_bf16_kernel<<<6144, 256, 0, stream>>>(ff_w2, w_ff2, LC * 256 * 1024);

    hipMemcpyAsync(h, x, (size_t)NTOTC * HC * 4, hipMemcpyDeviceToDevice, stream);
    hipMemcpyAsync(cur, pos, (size_t)NTOTC * 3 * 4, hipMemcpyDeviceToDevice, stream);
    conv_bf16_kernel<<<4096, 256, 0, stream>>>(x, h_bf, NTOTC * HC);
    // zero accumulators once; per-layer re-zero is fused into phi_h
    hipMemsetAsync(hmsg, 0, (size_t)NTOTC * HC * 4, stream);
    hipMemsetAsync(posupd, 0, (size_t)NTOTC * 3 * 4, stream);

    for (int l = 0; l < LC; l++) {
        // xcat = h @ [W1a;W1b]^T
        mgemm_kernel<0, false, false, true><<<dim3(NTOTC / 128, 4), 256, 0, stream>>>(
            h_bf, w_pe1s + (size_t)l * 512 * 256, zbias,
            nullptr, nullptr, xcat_bf, NTOTC, 512, HC);

        fused_edge_kernel<<<NEDGEC / 64, 256, 0, stream>>>(
            xcat_bf, cur, rowP, colP,
            w_last + (size_t)l * 256, pe_b1 + (size_t)l * HC,
            w_pe2 + (size_t)l * 256 * 256, pe_b2 + (size_t)l * HC,
            pe_lg + (size_t)l * HC, pe_lb + (size_t)l * HC,
            w_px1 + (size_t)l * 256 * 256, px_b1 + (size_t)l * HC,
            px_w2 + (size_t)l * HC, px_b2 + l,
            hmsg, posupd);

        // phi_h fully fused (+ cur update + posupd/hmsg re-zero)
        phi_h_fused_kernel<<<NTOTC / 64, 256, 0, stream>>>(
            h, hmsg,
            w_ph1 + (size_t)l * 256 * 256, ph_b1 + (size_t)l * HC,
            w_ph2 + (size_t)l * 256 * 256, ph_b2 + (size_t)l * HC,
            ph_lg + (size_t)l * HC, ph_lb + (size_t)l * HC,
            lnh_g + (size_t)l * HC, lnh_b + (size_t)l * HC, h, h_bf,
            cur, posupd, ps, l);

        // fused qkv projection + attention
        qkv_attn_kernel<<<NTOTC / 64, 256, 0, stream>>>(
            h_bf, w_ain + (size_t)l * 768 * 256, ain_b + (size_t)l * 3 * HC, o_bf);
        node_fused_kernel<<<NTOTC / 64, 256, 0, stream>>>(
            o_bf, w_aout + (size_t)l * 256 * 256, aout_b + (size_t)l * HC,
            lna_g + (size_t)l * HC, lna_b + (size_t)l * HC, h, h_bf);

        // feed-forward with residual
        mgemm_kernel<2, false, false, true><<<dim3(NTOTC / 128, 8), 256, 0, stream>>>(
            h_bf, w_ff1 + (size_t)l * 1024 * 256, ff_b1 + (size_t)l * 4 * HC,
            nullptr, nullptr, ff1_bf, NTOTC, 4 * HC, HC);
        mgemm_kernel<0, true, true, true><<<dim3(NTOTC / 128, 2), 256, 0, stream>>>(
            ff1_bf, w_ff2 + (size_t)l * 256 * 1024, ff_b2 + (size_t)l * HC,
            h, h, h_bf, NTOTC, HC, 4 * HC);
    }

    hipMemcpyAsync(d_out, h, (size_t)NTOTC * HC * 4, hipMemcpyDeviceToDevice, stream);
    hipMemcpyAsync((float*)d_out + (size_t)NTOTC * HC, cur, (size_t)NTOTC * 3 * 4,
                   hipMemcpyDeviceToDevice, stream);
}